// Round 9
// baseline (580.085 us; speedup 1.0000x reference)
//
#include <hip/hip_runtime.h>
#include <math.h>

#define HIDN 1024
#define NHEADS 16
#define DHEAD 64
#define FFD 4096
#define LN_EPS 1e-6f
#define NEGV -1e9f

typedef __bf16 bf16_t;
typedef __bf16 bf16x8 __attribute__((ext_vector_type(8)));
typedef float f32x4 __attribute__((ext_vector_type(4)));
typedef unsigned short ushort8 __attribute__((ext_vector_type(8)));
typedef unsigned short ushort4v __attribute__((ext_vector_type(4)));

__device__ __forceinline__ unsigned short f2bf(float f) {
    unsigned u = __float_as_uint(f);
    return (unsigned short)((u + 0x7FFFu + ((u >> 16) & 1u)) >> 16);
}
__device__ __forceinline__ float bf2f(unsigned short u) {
    return __uint_as_float((unsigned)u << 16);
}
__device__ __forceinline__ void gld16(const void* g, void* l) {
    __builtin_amdgcn_global_load_lds(
        (const __attribute__((address_space(1))) void*)g,
        (__attribute__((address_space(3))) void*)l, 16, 0, 0);
}

// ---------------------------------------------------------------------------
// 128^2 bf16 MFMA GEMM (proven rounds 6-8): BK=64, 4 waves, T2 swizzle,
// double-buffered LDS with issue-early staging. Used for N<=2048 shapes.
// ---------------------------------------------------------------------------
template<int RELU>
__global__ __launch_bounds__(256)
void gemm_mfma(const bf16_t* __restrict__ A, const bf16_t* __restrict__ W,
               const float* __restrict__ ba, const float* __restrict__ bb,
               const float* __restrict__ bc, const float* __restrict__ bd,
               unsigned short* __restrict__ Cb, int M, int N, int K)
{
    __shared__ __align__(16) bf16_t As[2][128 * 64];
    __shared__ __align__(16) bf16_t Bs[2][128 * 64];

    const int tid  = threadIdx.x;
    const int wid  = tid >> 6;
    const int lane = tid & 63;
    const int m0 = blockIdx.x * 128;
    const int n0 = blockIdx.y * 128;
    const int wm = (wid & 1) * 64;
    const int wn = (wid >> 1) * 64;

    const int sr = (wid << 3) + (lane >> 3);            // 0..31
    const int sk = (((lane & 7) ^ (lane >> 3)) * 8);
    const bf16_t* pa = A + (size_t)(m0 + sr) * K + sk;
    const bf16_t* pb = W + (size_t)(n0 + sr) * K + sk;
    const int lofs = (wid << 3) * 64;

    const int lr  = lane & 15;
    const int hi_ = lane >> 4;
    const int ch0 = ((hi_ + 0) ^ (lane & 7)) * 8;   // kk = 0
    const int ch1 = ((hi_ + 4) ^ (lane & 7)) * 8;   // kk = 32

    f32x4 acc[4][4];
    #pragma unroll
    for (int i = 0; i < 4; ++i)
        #pragma unroll
        for (int j = 0; j < 4; ++j) acc[i][j] = (f32x4){0.f, 0.f, 0.f, 0.f};

    auto stage = [&](int buf, int koff) {
        #pragma unroll
        for (int c = 0; c < 4; ++c) {
            gld16(pa + (size_t)c * 32 * K + koff, &As[buf][lofs + c * 32 * 64]);
            gld16(pb + (size_t)c * 32 * K + koff, &Bs[buf][lofs + c * 32 * 64]);
        }
    };
    auto compute = [&](int buf) {
        const bf16_t* fa = &As[buf][(wm + lr) * 64];
        const bf16_t* fb = &Bs[buf][(wn + lr) * 64];
        #pragma unroll
        for (int kk = 0; kk < 2; ++kk) {
            const int ch = kk ? ch1 : ch0;
            bf16x8 a[4], b[4];
            #pragma unroll
            for (int i = 0; i < 4; ++i) {
                a[i] = *(const bf16x8*)(fa + i * 16 * 64 + ch);
                b[i] = *(const bf16x8*)(fb + i * 16 * 64 + ch);
            }
            #pragma unroll
            for (int i = 0; i < 4; ++i)
                #pragma unroll
                for (int j = 0; j < 4; ++j)
                    acc[i][j] = __builtin_amdgcn_mfma_f32_16x16x32_bf16(
                        a[i], b[j], acc[i][j], 0, 0, 0);
        }
    };

    stage(0, 0);
    asm volatile("s_waitcnt vmcnt(0)" ::: "memory");
    __syncthreads();

    for (int k0 = 0; k0 < K; k0 += 128) {
        if (k0 + 64 < K) stage(1, k0 + 64);
        compute(0);
        asm volatile("s_waitcnt vmcnt(0)" ::: "memory");
        __syncthreads();
        if (k0 + 128 < K) stage(0, k0 + 128);
        compute(1);
        asm volatile("s_waitcnt vmcnt(0)" ::: "memory");
        __syncthreads();
    }

    const int seg = n0 >> 10;
    const float* bias = (seg == 0) ? ba : (seg == 1) ? bb : (seg == 2) ? bc : bd;
    const int nl = (n0 & 1023);
    const int er = wm + (lane >> 4) * 4;
    const int ec = wn + (lane & 15);
    float bv[4];
    #pragma unroll
    for (int j = 0; j < 4; ++j) bv[j] = bias[nl + ec + j * 16];
    #pragma unroll
    for (int i = 0; i < 4; ++i)
        #pragma unroll
        for (int j = 0; j < 4; ++j)
            #pragma unroll
            for (int r = 0; r < 4; ++r) {
                float v = acc[i][j][r] + bv[j];
                if (RELU) v = fmaxf(v, 0.f);
                Cb[(size_t)(m0 + er + i * 16 + r) * N + (n0 + ec + j * 16)] = f2bf(v);
            }
}

// ---------------------------------------------------------------------------
// 256^2 8-phase bf16 MFMA GEMM (T3+T4 port). BM=BN=256, BK=64, 512 threads =
// 8 waves (2M x 4N), per-wave 128x64 output. LDS 128 KB (2 dbuf x 32 KB x A,B).
// Per K-tile: 4 phases = (K-chunk, M-half) quadrants, each
//   {ds_read 4-8 x b128 | issue 4 gld_lds -> barrier -> setprio(1) -> 16 MFMA
//    -> setprio(0) -> barrier};
// B-frags live in registers across the two M-half phases. All 8 prefetch
// issues for tile t+1 front-loaded into phases 0-1, so the boundary vmcnt(0)
// fires ~2-3 phases after issue (loads complete under MFMA). T2 chunk-XOR
// swizzle (source pre-swizzled / read XOR). Bijective XCD swizzle on blockIdx.
// Requires: M%256==0, N%256==0, K%64==0, (M/256*N/256)%8==0.
// ---------------------------------------------------------------------------
template<int RELU>
__global__ __launch_bounds__(512, 1)
void gemm_mfma256(const bf16_t* __restrict__ A, const bf16_t* __restrict__ W,
                  const float* __restrict__ ba, const float* __restrict__ bb,
                  const float* __restrict__ bc, const float* __restrict__ bd,
                  unsigned short* __restrict__ Cb, int M, int N, int K)
{
    __shared__ __align__(16) bf16_t As[2][256 * 64];
    __shared__ __align__(16) bf16_t Bs[2][256 * 64];

    const int tid  = threadIdx.x;
    const int wid  = tid >> 6;        // 0..7
    const int lane = tid & 63;
    const int lo   = lane & 15;
    const int hi   = lane >> 4;

    // XCD-aware bijective block swizzle (grid size multiple of 8 by caller)
    const int GX = gridDim.x;
    const int id = blockIdx.y * GX + blockIdx.x;
    const int cpx = (GX * gridDim.y) >> 3;
    const int swz = (id & 7) * cpx + (id >> 3);
    const int m0 = (swz % GX) * 256;
    const int n0 = (swz / GX) * 256;

    const int wm = (wid & 1) * 128;   // wave M offset
    const int wn = (wid >> 1) * 64;   // wave N offset

    // staging: part i covers tile rows i*64 + (tid>>3), phys chunk tid&7.
    // source col chunk pre-swizzled: (tid&7) ^ ((tid>>3)&7).
    const int srow = tid >> 3;                           // 0..63
    const int ssk  = (((tid & 7) ^ (srow & 7)) * 8);
    const bf16_t* pa = A + (size_t)(m0 + srow) * K + ssk;
    const bf16_t* pb = W + (size_t)(n0 + srow) * K + ssk;
    const int lbase = (wid << 3) * 64;                   // wave-uniform, +part*64*64

    auto stageA = [&](int buf, int koff) {
        #pragma unroll
        for (int i = 0; i < 4; ++i)
            gld16(pa + (size_t)i * 64 * K + koff, &As[buf][i * 64 * 64 + lbase]);
    };
    auto stageB = [&](int buf, int koff) {
        #pragma unroll
        for (int i = 0; i < 4; ++i)
            gld16(pb + (size_t)i * 64 * K + koff, &Bs[buf][i * 64 * 64 + lbase]);
    };

    // fragment reads: row&7 == lo&7 (wm, wn, f*16 are multiples of 8)
    auto ldA = [&](int buf, int f, int c) -> bf16x8 {
        const int row = wm + f * 16 + lo;
        const int ch  = ((c * 4 + hi) ^ (lo & 7)) * 8;
        return *(const bf16x8*)&As[buf][row * 64 + ch];
    };
    auto ldB = [&](int buf, int g, int c) -> bf16x8 {
        const int row = wn + g * 16 + lo;
        const int ch  = ((c * 4 + hi) ^ (lo & 7)) * 8;
        return *(const bf16x8*)&Bs[buf][row * 64 + ch];
    };

    f32x4 acc[8][4];
    #pragma unroll
    for (int f = 0; f < 8; ++f)
        #pragma unroll
        for (int g = 0; g < 4; ++g) acc[f][g] = (f32x4){0.f, 0.f, 0.f, 0.f};

    // prologue: stage tile 0 into buf 0
    stageA(0, 0);
    stageB(0, 0);
    asm volatile("s_waitcnt vmcnt(0)" ::: "memory");
    __syncthreads();

    const int nt = K >> 6;
    for (int t = 0; t < nt; ++t) {
        const int buf = t & 1;
        const int knext = (t + 1) << 6;
        const bool pf = (t + 1 < nt);
        bf16x8 a0, a1, a2, a3, b0, b1, b2, b3;

        // ---- phase 0: (k-chunk 0, M-half 0) ----
        a0 = ldA(buf, 0, 0); a1 = ldA(buf, 1, 0); a2 = ldA(buf, 2, 0); a3 = ldA(buf, 3, 0);
        b0 = ldB(buf, 0, 0); b1 = ldB(buf, 1, 0); b2 = ldB(buf, 2, 0); b3 = ldB(buf, 3, 0);
        if (pf) stageA(buf ^ 1, knext);
        __syncthreads();
        __builtin_amdgcn_s_setprio(1);
        acc[0][0] = __builtin_amdgcn_mfma_f32_16x16x32_bf16(a0, b0, acc[0][0], 0, 0, 0);
        acc[0][1] = __builtin_amdgcn_mfma_f32_16x16x32_bf16(a0, b1, acc[0][1], 0, 0, 0);
        acc[0][2] = __builtin_amdgcn_mfma_f32_16x16x32_bf16(a0, b2, acc[0][2], 0, 0, 0);
        acc[0][3] = __builtin_amdgcn_mfma_f32_16x16x32_bf16(a0, b3, acc[0][3], 0, 0, 0);
        acc[1][0] = __builtin_amdgcn_mfma_f32_16x16x32_bf16(a1, b0, acc[1][0], 0, 0, 0);
        acc[1][1] = __builtin_amdgcn_mfma_f32_16x16x32_bf16(a1, b1, acc[1][1], 0, 0, 0);
        acc[1][2] = __builtin_amdgcn_mfma_f32_16x16x32_bf16(a1, b2, acc[1][2], 0, 0, 0);
        acc[1][3] = __builtin_amdgcn_mfma_f32_16x16x32_bf16(a1, b3, acc[1][3], 0, 0, 0);
        acc[2][0] = __builtin_amdgcn_mfma_f32_16x16x32_bf16(a2, b0, acc[2][0], 0, 0, 0);
        acc[2][1] = __builtin_amdgcn_mfma_f32_16x16x32_bf16(a2, b1, acc[2][1], 0, 0, 0);
        acc[2][2] = __builtin_amdgcn_mfma_f32_16x16x32_bf16(a2, b2, acc[2][2], 0, 0, 0);
        acc[2][3] = __builtin_amdgcn_mfma_f32_16x16x32_bf16(a2, b3, acc[2][3], 0, 0, 0);
        acc[3][0] = __builtin_amdgcn_mfma_f32_16x16x32_bf16(a3, b0, acc[3][0], 0, 0, 0);
        acc[3][1] = __builtin_amdgcn_mfma_f32_16x16x32_bf16(a3, b1, acc[3][1], 0, 0, 0);
        acc[3][2] = __builtin_amdgcn_mfma_f32_16x16x32_bf16(a3, b2, acc[3][2], 0, 0, 0);
        acc[3][3] = __builtin_amdgcn_mfma_f32_16x16x32_bf16(a3, b3, acc[3][3], 0, 0, 0);
        __builtin_amdgcn_s_setprio(0);
        __syncthreads();

        // ---- phase 1: (k-chunk 0, M-half 1), reuse b0-b3 ----
        a0 = ldA(buf, 4, 0); a1 = ldA(buf, 5, 0); a2 = ldA(buf, 6, 0); a3 = ldA(buf, 7, 0);
        if (pf) stageB(buf ^ 1, knext);
        __syncthreads();
        __builtin_amdgcn_s_setprio(1);
        acc[4][0] = __builtin_amdgcn_mfma_f32_16x16x32_bf16(a0, b0, acc[4][0], 0, 0, 0);
        acc[4][1] = __builtin_amdgcn_mfma_f32_16x16x32_bf16(a0, b1, acc[4][1], 0, 0, 0);
        acc[4][2] = __builtin_amdgcn_mfma_f32_16x16x32_bf16(a0, b2, acc[4][2], 0, 0, 0);
        acc[4][3] = __builtin_amdgcn_mfma_f32_16x16x32_bf16(a0, b3, acc[4][3], 0, 0, 0);
        acc[5][0] = __builtin_amdgcn_mfma_f32_16x16x32_bf16(a1, b0, acc[5][0], 0, 0, 0);
        acc[5][1] = __builtin_amdgcn_mfma_f32_16x16x32_bf16(a1, b1, acc[5][1], 0, 0, 0);
        acc[5][2] = __builtin_amdgcn_mfma_f32_16x16x32_bf16(a1, b2, acc[5][2], 0, 0, 0);
        acc[5][3] = __builtin_amdgcn_mfma_f32_16x16x32_bf16(a1, b3, acc[5][3], 0, 0, 0);
        acc[6][0] = __builtin_amdgcn_mfma_f32_16x16x32_bf16(a2, b0, acc[6][0], 0, 0, 0);
        acc[6][1] = __builtin_amdgcn_mfma_f32_16x16x32_bf16(a2, b1, acc[6][1], 0, 0, 0);
        acc[6][2] = __builtin_amdgcn_mfma_f32_16x16x32_bf16(a2, b2, acc[6][2], 0, 0, 0);
        acc[6][3] = __builtin_amdgcn_mfma_f32_16x16x32_bf16(a2, b3, acc[6][3], 0, 0, 0);
        acc[7][0] = __builtin_amdgcn_mfma_f32_16x16x32_bf16(a3, b0, acc[7][0], 0, 0, 0);
        acc[7][1] = __builtin_amdgcn_mfma_f32_16x16x32_bf16(a3, b1, acc[7][1], 0, 0, 0);
        acc[7][2] = __builtin_amdgcn_mfma_f32_16x16x32_bf16(a3, b2, acc[7][2], 0, 0, 0);
        acc[7][3] = __builtin_amdgcn_mfma_f32_16x16x32_bf16(a3, b3, acc[7][3], 0, 0, 0);
        __builtin_amdgcn_s_setprio(0);
        __syncthreads();

        // ---- phase 2: (k-chunk 1, M-half 0) ----
        a0 = ldA(buf, 0, 1); a1 = ldA(buf, 1, 1); a2 = ldA(buf, 2, 1); a3 = ldA(buf, 3, 1);
        b0 = ldB(buf, 0, 1); b1 = ldB(buf, 1, 1); b2 = ldB(buf, 2, 1); b3 = ldB(buf, 3, 1);
        __syncthreads();
        __builtin_amdgcn_s_setprio(1);
        acc[0][0] = __builtin_amdgcn_mfma_f32_16x16x32_bf16(a0, b0, acc[0][0], 0, 0, 0);
        acc[0][1] = __builtin_amdgcn_mfma_f32_16x16x32_bf16(a0, b1, acc[0][1], 0, 0, 0);
        acc[0][2] = __builtin_amdgcn_mfma_f32_16x16x32_bf16(a0, b2, acc[0][2], 0, 0, 0);
        acc[0][3] = __builtin_amdgcn_mfma_f32_16x16x32_bf16(a0, b3, acc[0][3], 0, 0, 0);
        acc[1][0] = __builtin_amdgcn_mfma_f32_16x16x32_bf16(a1, b0, acc[1][0], 0, 0, 0);
        acc[1][1] = __builtin_amdgcn_mfma_f32_16x16x32_bf16(a1, b1, acc[1][1], 0, 0, 0);
        acc[1][2] = __builtin_amdgcn_mfma_f32_16x16x32_bf16(a1, b2, acc[1][2], 0, 0, 0);
        acc[1][3] = __builtin_amdgcn_mfma_f32_16x16x32_bf16(a1, b3, acc[1][3], 0, 0, 0);
        acc[2][0] = __builtin_amdgcn_mfma_f32_16x16x32_bf16(a2, b0, acc[2][0], 0, 0, 0);
        acc[2][1] = __builtin_amdgcn_mfma_f32_16x16x32_bf16(a2, b1, acc[2][1], 0, 0, 0);
        acc[2][2] = __builtin_amdgcn_mfma_f32_16x16x32_bf16(a2, b2, acc[2][2], 0, 0, 0);
        acc[2][3] = __builtin_amdgcn_mfma_f32_16x16x32_bf16(a2, b3, acc[2][3], 0, 0, 0);
        acc[3][0] = __builtin_amdgcn_mfma_f32_16x16x32_bf16(a3, b0, acc[3][0], 0, 0, 0);
        acc[3][1] = __builtin_amdgcn_mfma_f32_16x16x32_bf16(a3, b1, acc[3][1], 0, 0, 0);
        acc[3][2] = __builtin_amdgcn_mfma_f32_16x16x32_bf16(a3, b2, acc[3][2], 0, 0, 0);
        acc[3][3] = __builtin_amdgcn_mfma_f32_16x16x32_bf16(a3, b3, acc[3][3], 0, 0, 0);
        __builtin_amdgcn_s_setprio(0);
        __syncthreads();

        // ---- phase 3: (k-chunk 1, M-half 1), reuse b0-b3 ----
        a0 = ldA(buf, 4, 1); a1 = ldA(buf, 5, 1); a2 = ldA(buf, 6, 1); a3 = ldA(buf, 7, 1);
        __syncthreads();
        __builtin_amdgcn_s_setprio(1);
        acc[4][0] = __builtin_amdgcn_mfma_f32_16x16x32_bf16(a0, b0, acc[4][0], 0, 0, 0);
        acc[4][1] = __builtin_amdgcn_mfma_f32_16x16x32_bf16(a0, b1, acc[4][1], 0, 0, 0);
        acc[4][2] = __builtin_amdgcn_mfma_f32_16x16x32_bf16(a0, b2, acc[4][2], 0, 0, 0);
        acc[4][3] = __builtin_amdgcn_mfma_f32_16x16x32_bf16(a0, b3, acc[4][3], 0, 0, 0);
        acc[5][0] = __builtin_amdgcn_mfma_f32_16x16x32_bf16(a1, b0, acc[5][0], 0, 0, 0);
        acc[5][1] = __builtin_amdgcn_mfma_f32_16x16x32_bf16(a1, b1, acc[5][1], 0, 0, 0);
        acc[5][2] = __builtin_amdgcn_mfma_f32_16x16x32_bf16(a1, b2, acc[5][2], 0, 0, 0);
        acc[5][3] = __builtin_amdgcn_mfma_f32_16x16x32_bf16(a1, b3, acc[5][3], 0, 0, 0);
        acc[6][0] = __builtin_amdgcn_mfma_f32_16x16x32_bf16(a2, b0, acc[6][0], 0, 0, 0);
        acc[6][1] = __builtin_amdgcn_mfma_f32_16x16x32_bf16(a2, b1, acc[6][1], 0, 0, 0);
        acc[6][2] = __builtin_amdgcn_mfma_f32_16x16x32_bf16(a2, b2, acc[6][2], 0, 0, 0);
        acc[6][3] = __builtin_amdgcn_mfma_f32_16x16x32_bf16(a2, b3, acc[6][3], 0, 0, 0);
        acc[7][0] = __builtin_amdgcn_mfma_f32_16x16x32_bf16(a3, b0, acc[7][0], 0, 0, 0);
        acc[7][1] = __builtin_amdgcn_mfma_f32_16x16x32_bf16(a3, b1, acc[7][1], 0, 0, 0);
        acc[7][2] = __builtin_amdgcn_mfma_f32_16x16x32_bf16(a3, b2, acc[7][2], 0, 0, 0);
        acc[7][3] = __builtin_amdgcn_mfma_f32_16x16x32_bf16(a3, b3, acc[7][3], 0, 0, 0);
        __builtin_amdgcn_s_setprio(0);
        // ---- boundary: prefetched loads (issued phases 0-1) must land ----
        asm volatile("s_waitcnt vmcnt(0)" ::: "memory");
        __syncthreads();
    }

    // epilogue
    const int seg = n0 >> 10;
    const float* bias = (seg == 0) ? ba : (seg == 1) ? bb : (seg == 2) ? bc : bd;
    const int nl = (n0 & 1023);
    float bv[4];
    #pragma unroll
    for (int g = 0; g < 4; ++g) bv[g] = bias[nl + wn + g * 16 + lo];
    #pragma unroll
    for (int f = 0; f < 8; ++f)
        #pragma unroll
        for (int g = 0; g < 4; ++g)
            #pragma unroll
            for (int r = 0; r < 4; ++r) {
                float v = acc[f][g][r] + bv[g];
                if (RELU) v = fmaxf(v, 0.f);
                Cb[(size_t)(m0 + wm + f * 16 + hi * 4 + r) * N
                   + (n0 + wn + g * 16 + lo)] = f2bf(v);
            }
}

// ---------------------------------------------------------------------------
// MFMA attention v2 (unchanged round 8): one block per (head,batch), 8 waves,
// K/V fetched once, swizzled LDS, async-STAGE split.
// ---------------------------------------------------------------------------
template<int HAS_MASK>
__global__ __launch_bounds__(512, 2)
void attn_mfma(const bf16_t* __restrict__ Q, const bf16_t* __restrict__ K,
               const bf16_t* __restrict__ V, int qstride, int kvstride,
               const int* __restrict__ mask,
               unsigned short* __restrict__ O, int Lk)
{
    __shared__ __align__(16) unsigned short Ks[64][72];    // [k][d] swz
    __shared__ __align__(16) unsigned short Vt[64][72];    // [d][k] swz
    __shared__ __align__(16) unsigned short Ps[128][72];   // [q][k] linear
    __shared__ int smask[64];

    const int tid  = threadIdx.x;
    const int wid  = tid >> 6;
    const int lane = tid & 63;
    const int lo   = lane & 15;
    const int hi   = lane >> 4;
    const int h    = blockIdx.x;
    const int b    = blockIdx.y;
    const int Lq   = 512;

    bf16x8 qf[4][2];
    #pragma unroll
    for (int s4 = 0; s4 < 4; ++s4) {
        const bf16_t* qp = Q + (size_t)(b*Lq + s4*128 + wid*16 + lo) * qstride
                             + h*DHEAD + hi*8;
        qf[s4][0] = *(const bf16x8*)qp;
        qf[s4][1] = *(const bf16x8*)(qp + 32);
    }

    float mrun[4][4], lrun[4][4];
    f32x4 Oc[4][4];
    #pragma unroll
    for (int s4 = 0; s4 < 4; ++s4)
        #pragma unroll
        for (int r = 0; r < 4; ++r) {
            mrun[s4][r] = -INFINITY; lrun[s4][r] = 0.f;
            Oc[s4][r] = (f32x4){0.f, 0.f, 0.f, 0.f};
        }

    ushort8 r0, r1;
    int mreg = 0;

    auto load_tile = [&](int k0) {
        if (tid < 256) {
            const int sr = tid >> 2, sc = (tid & 3) * 16;
            const unsigned short* kp = (const unsigned short*)
                (K + (size_t)(b*Lk + k0 + sr) * kvstride + h*DHEAD + sc);
            r0 = *(const ushort8*)kp;
            r1 = *(const ushort8*)(kp + 8);
        } else {
            const int t2 = tid - 256, sr = t2 >> 2, sc = (t2 & 3) * 16;
            const unsigned short* vp = (const unsigned short*)
                (V + (size_t)(b*Lk + k0 + sr) * kvstride + h*DHEAD + sc);
            r0 = *(const ushort8*)vp;
            r1 = *(const ushort8*)(vp + 8);
        }
        if (HAS_MASK && tid < 64) mreg = mask[b*Lk + k0 + tid];
    };
    auto store_tile = [&]() {
        if (tid < 256) {
            const int sr = tid >> 2, sc = (tid & 3) * 16;
            const int x = ((sr >> 3) & 7) << 3;
            *(ushort8*)&Ks[sr][sc ^ x]       = r0;
            *(ushort8*)&Ks[sr][(sc + 8) ^ x] = r1;
        } else {
            const int t2 = tid - 256, sr = t2 >> 2, sc = (t2 & 3) * 16;
            #pragma unroll
            for (int t = 0; t < 8; ++t) {
                const int d0 = sc + t, d1 = sc + 8 + t;
                Vt[d0][sr ^ (((d0 >> 3) & 7) << 3)] = r0[t];
                Vt[d1][sr ^ (((d1 >> 3) & 7) << 3)] = r1[t];
            }
        }
        if (HAS_MASK && tid < 64) smask[tid] = mreg;
    };

    load_tile(0);
    store_tile();
    __syncthreads();

    int k0 = 0;
    while (true) {
        const bool more = (k0 + 64 < Lk);
        if (more) load_tile(k0 + 64);

        #pragma unroll
        for (int s4 = 0; s4 < 4; ++s4) {
            f32x4 sv[4];
            #pragma unroll
            for (int j = 0; j < 4; ++j) sv[j] = (f32x4){0.f, 0.f, 0.f, 0.f};
            #pragma unroll
            for (int kk = 0; kk < 2; ++kk) {
                #pragma unroll
                for (int j = 0; j < 4; ++j) {
                    const int krow = j*16 + lo;
                    const int kcol = (kk*32 + hi*8) ^ (((krow >> 3) & 7) << 3);
                    bf16x8 bfrag = *(const bf16x8*)&Ks[krow][kcol];
                    sv[j] = __builtin_amdgcn_mfma_f32_16x16x32_bf16(
                        qf[s4][kk], bfrag, sv[j], 0, 0, 0);
                }
            }
            #pragma unroll
            for (int j = 0; j < 4; ++j) {
                bool msk = HAS_MASK ? (smask[j*16 + lo] != 0) : false;
                #pragma unroll
                for (int r = 0; r < 4; ++r) {
                    float x = sv[j][r] * 0.125f;
                    sv[j][r] = msk ? NEGV : x;
                }
            }
            #pragma unroll
            for (int r = 0; r < 4; ++r) {
                float tm = fmaxf(fmaxf(sv[0][r], sv[1][r]), fmaxf(sv[2][r], sv[3][r]));
                #pragma unroll
                for (int m = 1; m < 16; m <<= 1) tm = fmaxf(tm, __shfl_xor(tm, m));
                float mnew = fmaxf(mrun[s4][r], tm);
                float f = __expf(mrun[s4][r] - mnew);
                float ps = 0.f;
                #pragma unroll
                for (int j = 0; j < 4; ++j) {
                    float p = __expf(sv[j][r] - mnew);
                    sv[j][r] = p;
                    ps += p;
                }
                #pragma unroll
                for (int m = 1; m < 16; m <<= 1) ps += __shfl_xor(ps, m);
                lrun[s4][r] = lrun[s4][r] * f + ps;
                mrun[s4][r] = mnew;
                #pragma unroll
                for (int n = 0; n < 4; ++n) Oc[s4][n][r] *= f;
                #pragma unroll
                for (int j = 0; j < 4; ++j)
                    Ps[wid*16 + hi*4 + r][j*16 + lo] = f2bf(sv[j][r]);
            }
            #pragma unroll
            for (int kk = 0; kk < 2; ++kk) {
                bf16x8 pa = *(const bf16x8*)&Ps[wid*16 + lo][kk*32 + hi*8];
                #pragma unroll
                for (int n = 0; n < 4; ++n) {
                    const int vrow = n*16 + lo;
                    const int vcol = (kk*32 + hi*8) ^ (((vrow >> 3) & 7) << 3);
                    bf16x8 vf = *(const bf16x8*)&Vt[vrow][vcol];
                    Oc[s4][n] = __builtin_amdgcn_mfma_f32_16x16x32_bf16(
                        pa, vf, Oc[s4][n], 0, 0, 0);
                }
            }
        }

        if (!more) break;
        __syncthreads();
        store_tile();
        __syncthreads();
        k0 += 64;
    }

    #pragma unroll
    for (int s4 = 0; s4 < 4; ++s4)
        #pragma unroll
        for (int r = 0; r < 4; ++r) {
            float inv = 1.f / lrun[s4][r];
            const size_t row = (size_t)(b*Lq + s4*128 + wid*16 + hi*4 + r) * HIDN
                             + h*DHEAD;
            #pragma unroll
            for (int n = 0; n < 4; ++n)
                O[row + n*16 + lo] = f2bf(Oc[s4][n][r] * inv);
        }
}

// ---------------------------------------------------------------------------
// LayerNorm(X + R): X,R bf16; stats fp32; write bf16 (in-place ok) and/or f32.
// ---------------------------------------------------------------------------
template<int WF32, int WBF>
__global__ __launch_bounds__(256)
void ln_res_b(const unsigned short* __restrict__ X, const unsigned short* __restrict__ R,
              const float* __restrict__ G, const float* __restrict__ Bv,
              unsigned short* __restrict__ OutB, float* __restrict__ OutF)
{
    const int row = blockIdx.x;
    const int tid = threadIdx.x;
    const size_t base = (size_t)row * HIDN + tid * 4;
    ushort4v xv = *(const ushort4v*)(X + base);
    ushort4v rv = *(const ushort4v*)(R + base);
    float y[4];
    #pragma unroll
    for (int t = 0; t < 4; ++t) y[t] = bf2f(xv[t]) + bf2f(rv[t]);
    float s1 = y[0] + y[1] + y[2] + y[3];
    float s2 = y[0]*y[0] + y[1]*y[1] + y[2]*y[2] + y[3]*y[3];
    #pragma unroll
    for (int m = 1; m < 64; m <<= 1) {
        s1 += __shfl_xor(s1, m);
        s2 += __shfl_xor(s2, m);
    }
    __shared__ float red1[4], red2[4];
    const int wave = tid >> 6, lane = tid & 63;
    if (lane == 0) { red1[wave] = s1; red2[wave] = s2; }
    __syncthreads();
    s1 = red1[0] + red1[1] + red1[2] + red1[3];
    s2 = red2[0] + red2[1] + red2[2] + red2[3];
    const float mean = s1 * (1.f / HIDN);
    const float var  = s2 * (1.f / HIDN) - mean * mean;
    const float inv  = rsqrtf(var + LN_EPS);
    float4 gv = *(const float4*)(G + tid*4);
    float4 bv = *(const float4*)(Bv + tid*4);
    float o[4];
    o[0] = gv.x * (y[0]-mean) * inv + bv.x;
    o[1] = gv.y * (y[1]-mean) * inv + bv.y;
    o[2] = gv.z * (y[2]-mean) * inv + bv.z;
    o[3] = gv.w * (y[3]-mean) * inv + bv.w;
    if (WBF) {
        ushort4v ob;
        #pragma unroll
        for (int t = 0; t < 4; ++t) ob[t] = f2bf(o[t]);
        *(ushort4v*)(OutB + base) = ob;
    }
    if (WF32) {
        float4 of = {o[0], o[1], o[2], o[3]};
        *(float4*)(OutF + base) = of;
    }
}

// ---------------------------------------------------------------------------
// One-shot fp32 -> bf16 conversion of 1Mi-element units (weights + acts).
// ---------------------------------------------------------------------------
struct CvtArgs {
    const float* src[32];
    unsigned short* dst[32];
};

__global__ __launch_bounds__(256)
void cvt_units(CvtArgs args)
{
    const float* s = args.src[blockIdx.y];
    unsigned short* d = args.dst[blockIdx.y];
    const int i = blockIdx.x * 256 + threadIdx.x;   // 0..131071
    const float4* p = (const float4*)s + (size_t)i * 2;
    float4 a = p[0], b = p[1];
    ushort8 o;
    o[0] = f2bf(a.x); o[1] = f2bf(a.y); o[2] = f2bf(a.z); o[3] = f2bf(a.w);
    o[4] = f2bf(b.x); o[5] = f2bf(b.y); o[6] = f2bf(b.z); o[7] = f2bf(b.w);
    ((ushort8*)d)[i] = o;
}

// ---------------------------------------------------------------------------
extern "C" void kernel_launch(void* const* d_in, const int* in_sizes, int n_in,
                              void* d_out, int out_size, void* d_ws, size_t ws_size,
                              hipStream_t stream)
{
    const float* img   = (const float*)d_in[0];
    const float* ques  = (const float*)d_in[1];
    const float* kg    = (const float*)d_in[2];
    const int*   qmask = (const int*)d_in[3];
    const int*   kmask = (const int*)d_in[4];
    const float* qw = (const float*)d_in[5];
    const float* qb = (const float*)d_in[6];
    const float* kw = (const float*)d_in[7];
    const float* kb = (const float*)d_in[8];
    const float* vw = (const float*)d_in[9];
    const float* vb = (const float*)d_in[10];
    const float* ow = (const float*)d_in[11];
    const float* ob = (const float*)d_in[12];
    const float* w1 = (const float*)d_in[13];
    const float* b1 = (const float*)d_in[14];
    const float* w2 = (const float*)d_in[15];
    const float* b2 = (const float*)d_in[16];
    const float* lng = (const float*)d_in[17];
    const float* lnb = (const float*)d_in[18];
    float* out = (float*)d_out;

    const int B = 16;
    const int NX = B * 512;                    // 8192 rows
    const size_t WSTEP = (size_t)1024 * 1024;
    const size_t MB = (size_t)1 << 20;
    const size_t MELEM = (size_t)1024 * 1024;

    char* wsb = (char*)d_ws;
    unsigned short* xb    = (unsigned short*)(wsb);            // 16 MB
    unsigned short* bM    = (unsigned short*)(wsb + 16*MB);    // 16 MB
    unsigned short* bOb   = (unsigned short*)(wsb + 32*MB);    // 16 MB
    unsigned short* quesb = (unsigned short*)(wsb + 48*MB);    //  2 MB
    unsigned short* kgb   = (unsigned short*)(wsb + 50*MB);    //  4 MB
    unsigned short* wa    = (unsigned short*)(wsb + 56*MB);    // 40 MB weight arena
    unsigned short* bQKV  = (unsigned short*)(wsb + 96*MB);    // 48 MB
    unsigned short* bKV   = (unsigned short*)(wsb + 144*MB);   //  8 MB
    unsigned short* hb    = (unsigned short*)(wsb + 96*MB);    // 64 MB, overlays bQKV/bKV

    CvtArgs ca;
    int u = 0;
    auto addu = [&](const float* src, int melems, unsigned short* dst) {
        for (int i = 0; i < melems; ++i) {
            ca.src[u] = src + (size_t)i * MELEM;
            ca.dst[u] = dst + (size_t)i * MELEM;
            ++u;
        }
    };
    addu(qw + 0*WSTEP, 1, wa + 0*MELEM);
    addu(kw + 0*WSTEP, 1, wa + 1*MELEM);
    addu(vw + 0*WSTEP, 1, wa + 2*MELEM);
    addu(qw + 1*WSTEP, 1, wa + 3*MELEM);
    addu(kw + 1*WSTEP, 1, wa + 4*MELEM);
    addu(vw + 1*WSTEP, 1, wa + 5*MELEM);
    addu(qw + 2*WSTEP, 1, wa + 6*MELEM);
    addu(kw + 2*WSTEP, 1, wa + 7*MELEM);
    addu(vw + 2*WSTEP, 1, wa + 8*MELEM);
    addu(ow + 0*WSTEP, 1, wa + 9*MELEM);
    addu(ow + 1*WSTEP, 1, wa + 10*MELEM);
    addu(ow + 2*WSTEP, 1, wa + 11*MELEM);
    addu(w1, 4, wa + 12*MELEM);
    addu(w2, 4, wa + 16*MELEM);
    addu(img,  8, xb);
    addu(ques, 1, quesb);
    addu(kg,   2, kgb);

    dim3 blk(256);
    cvt_units<<<dim3(512, u), blk, 0, stream>>>(ca);

    auto gemm = [&](const unsigned short* A, const unsigned short* W,
                    const float* ba, const float* bb_, const float* bc, const float* bd,
                    unsigned short* C, int M, int N, int K, int relu) {
        // 256^2 8-phase kernel for the big shapes (grid multiple of 8)
        if ((M % 256) == 0 && (N % 256) == 0 && ((M / 256) * (N / 256)) % 8 == 0
            && N >= 3072) {
            dim3 grid(M / 256, N / 256);
            if (relu) gemm_mfma256<1><<<grid, dim3(512), 0, stream>>>(
                (const bf16_t*)A, (const bf16_t*)W, ba, bb_, bc, bd, C, M, N, K);
            else      gemm_mfma256<0><<<grid, dim3(512), 0, stream>>>(
                (const bf16_t*)A, (const bf16_t*)W, ba, bb_, bc, bd, C, M, N, K);
            return;
        }
        dim3 grid(M / 128, N / 128);
        if (relu) gemm_mfma<1><<<grid, blk, 0, stream>>>(
            (const bf16_t*)A, (const bf16_t*)W, ba, bb_, bc, bd, C, M, N, K);
        else      gemm_mfma<0><<<grid, blk, 0, stream>>>(
            (const bf16_t*)A, (const bf16_t*)W, ba, bb_, bc, bd, C, M, N, K);
    };

    const unsigned short* Akv[3] = {xb, quesb, kgb};
    const int Mkv[3] = {NX, B * 64, B * 128};
    const int Lk[3]  = {512, 64, 128};

    dim3 ablk(512);
    dim3 agrid(NHEADS, B);

    for (int t = 0; t < 3; ++t) {
        if (t == 0) {
            gemm(xb, wa + 0*MELEM, qb + 0, kb + 0, vb + 0, vb + 0,
                 bQKV, NX, 3072, 1024, 0);
            attn_mfma<0><<<agrid, ablk, 0, stream>>>(
                (const bf16_t*)bQKV, (const bf16_t*)bQKV + 1024, (const bf16_t*)bQKV + 2048,
                3072, 3072, nullptr, bOb, Lk[t]);
        } else {
            gemm(xb, wa + (t == 1 ? 3 : 6)*MELEM,
                 qb + t*1024, qb + t*1024, qb + t*1024, qb + t*1024,
                 bQKV, NX, 1024, 1024, 0);
            gemm(Akv[t], wa + (t == 1 ? 4 : 7)*MELEM,
                 kb + t*1024, vb + t*1024, vb + t*1024, vb + t*1024,
                 bKV, Mkv[t], 2048, 1024, 0);
            attn_mfma<1><<<agrid, ablk, 0, stream>>>(
                (const bf16_t*)bQKV, (const bf16_t*)bKV, (const bf16_t*)bKV + 1024,
                1024, 2048, (t == 1 ? qmask : kmask), bOb, Lk[t]);
        }
        gemm(bOb, wa + (9 + t)*MELEM,
             ob + t*1024, ob + t*1024, ob + t*1024, ob + t*1024,
             bM, NX, 1024, 1024, 0);
        ln_res_b<0,1><<<NX, blk, 0, stream>>>(xb, bM, lng + t*1024, lnb + t*1024, xb, nullptr);
    }

    // FFN
    gemm(xb, wa + 12*MELEM, b1, b1 + 1024, b1 + 2048, b1 + 3072, hb, NX, FFD, 1024, 1);
    gemm(hb, wa + 16*MELEM, b2, b2, b2, b2, bM, NX, 1024, 4096, 0);
    ln_res_b<1,0><<<NX, blk, 0, stream>>>(xb, bM, lng + 3*1024, lnb + 3*1024, nullptr, out);
}

// Round 10
// 516.541 us; speedup vs baseline: 1.1230x; 1.1230x over previous
//
#include <hip/hip_runtime.h>
#include <math.h>

#define HIDN 1024
#define NHEADS 16
#define DHEAD 64
#define FFD 4096
#define LN_EPS 1e-6f
#define NEGV -1e9f

typedef __bf16 bf16_t;
typedef __bf16 bf16x8 __attribute__((ext_vector_type(8)));
typedef float f32x4 __attribute__((ext_vector_type(4)));
typedef unsigned short ushort8 __attribute__((ext_vector_type(8)));
typedef unsigned short ushort4v __attribute__((ext_vector_type(4)));

__device__ __forceinline__ unsigned short f2bf(float f) {
    unsigned u = __float_as_uint(f);
    return (unsigned short)((u + 0x7FFFu + ((u >> 16) & 1u)) >> 16);
}
__device__ __forceinline__ float bf2f(unsigned short u) {
    return __uint_as_float((unsigned)u << 16);
}
__device__ __forceinline__ void gld16(const void* g, void* l) {
    __builtin_amdgcn_global_load_lds(
        (const __attribute__((address_space(1))) void*)g,
        (__attribute__((address_space(3))) void*)l, 16, 0, 0);
}

// ---------------------------------------------------------------------------
// 128^2 bf16 MFMA GEMM (proven rounds 6-8): BK=64, 4 waves, T2 swizzle,
// double-buffered LDS with issue-early staging. Used for N<=2048 shapes.
// ---------------------------------------------------------------------------
template<int RELU>
__global__ __launch_bounds__(256)
void gemm_mfma(const bf16_t* __restrict__ A, const bf16_t* __restrict__ W,
               const float* __restrict__ ba, const float* __restrict__ bb,
               const float* __restrict__ bc, const float* __restrict__ bd,
               unsigned short* __restrict__ Cb, int M, int N, int K)
{
    __shared__ __align__(16) bf16_t As[2][128 * 64];
    __shared__ __align__(16) bf16_t Bs[2][128 * 64];

    const int tid  = threadIdx.x;
    const int wid  = tid >> 6;
    const int lane = tid & 63;
    const int m0 = blockIdx.x * 128;
    const int n0 = blockIdx.y * 128;
    const int wm = (wid & 1) * 64;
    const int wn = (wid >> 1) * 64;

    const int sr = (wid << 3) + (lane >> 3);            // 0..31
    const int sk = (((lane & 7) ^ (lane >> 3)) * 8);
    const bf16_t* pa = A + (size_t)(m0 + sr) * K + sk;
    const bf16_t* pb = W + (size_t)(n0 + sr) * K + sk;
    const int lofs = (wid << 3) * 64;

    const int lr  = lane & 15;
    const int hi_ = lane >> 4;
    const int ch0 = ((hi_ + 0) ^ (lane & 7)) * 8;   // kk = 0
    const int ch1 = ((hi_ + 4) ^ (lane & 7)) * 8;   // kk = 32

    f32x4 acc[4][4];
    #pragma unroll
    for (int i = 0; i < 4; ++i)
        #pragma unroll
        for (int j = 0; j < 4; ++j) acc[i][j] = (f32x4){0.f, 0.f, 0.f, 0.f};

    auto stage = [&](int buf, int koff) {
        #pragma unroll
        for (int c = 0; c < 4; ++c) {
            gld16(pa + (size_t)c * 32 * K + koff, &As[buf][lofs + c * 32 * 64]);
            gld16(pb + (size_t)c * 32 * K + koff, &Bs[buf][lofs + c * 32 * 64]);
        }
    };
    auto compute = [&](int buf) {
        const bf16_t* fa = &As[buf][(wm + lr) * 64];
        const bf16_t* fb = &Bs[buf][(wn + lr) * 64];
        #pragma unroll
        for (int kk = 0; kk < 2; ++kk) {
            const int ch = kk ? ch1 : ch0;
            bf16x8 a[4], b[4];
            #pragma unroll
            for (int i = 0; i < 4; ++i) {
                a[i] = *(const bf16x8*)(fa + i * 16 * 64 + ch);
                b[i] = *(const bf16x8*)(fb + i * 16 * 64 + ch);
            }
            #pragma unroll
            for (int i = 0; i < 4; ++i)
                #pragma unroll
                for (int j = 0; j < 4; ++j)
                    acc[i][j] = __builtin_amdgcn_mfma_f32_16x16x32_bf16(
                        a[i], b[j], acc[i][j], 0, 0, 0);
        }
    };

    stage(0, 0);
    asm volatile("s_waitcnt vmcnt(0)" ::: "memory");
    __syncthreads();

    for (int k0 = 0; k0 < K; k0 += 128) {
        if (k0 + 64 < K) stage(1, k0 + 64);
        compute(0);
        asm volatile("s_waitcnt vmcnt(0)" ::: "memory");
        __syncthreads();
        if (k0 + 128 < K) stage(0, k0 + 128);
        compute(1);
        asm volatile("s_waitcnt vmcnt(0)" ::: "memory");
        __syncthreads();
    }

    const int seg = n0 >> 10;
    const float* bias = (seg == 0) ? ba : (seg == 1) ? bb : (seg == 2) ? bc : bd;
    const int nl = (n0 & 1023);
    const int er = wm + (lane >> 4) * 4;
    const int ec = wn + (lane & 15);
    float bv[4];
    #pragma unroll
    for (int j = 0; j < 4; ++j) bv[j] = bias[nl + ec + j * 16];
    #pragma unroll
    for (int i = 0; i < 4; ++i)
        #pragma unroll
        for (int j = 0; j < 4; ++j)
            #pragma unroll
            for (int r = 0; r < 4; ++r) {
                float v = acc[i][j][r] + bv[j];
                if (RELU) v = fmaxf(v, 0.f);
                Cb[(size_t)(m0 + er + i * 16 + r) * N + (n0 + ec + j * 16)] = f2bf(v);
            }
}

// ---------------------------------------------------------------------------
// 256^2 8-phase bf16 MFMA GEMM, round 10: RAW s_barrier + hand waitcnt
// (round 9's __syncthreads drained vmcnt at every barrier, defeating T4).
// Per phase: {ds_read regs | issue prefetch -> s_barrier -> lgkmcnt(0) ->
// sched_barrier(0) -> setprio(1) -> 16 MFMA -> setprio(0) -> s_barrier}.
// vmcnt(0) ONCE per K-tile (end of phase 3): 8 prefetch loads stay in flight
// across ~3 MFMA phases. Buffer-swap safety: reads of buf^1 only after
// boundary vmcnt(0)+barrier; ds_reads of a tile are lgkm-complete before its
// final barrier so next tile may overwrite buf^1.
// XCD swizzle: 8 chunks of (8 m-blocks x GY/2 n-blocks) -> per-XCD fetch
// ~8 A-panels + GY/2 W-panels (round 9's m-sweep made each XCD read ALL of A).
// Requires: (M/256)%8==0, (N/256)%2==0, K%64==0.
// ---------------------------------------------------------------------------
#define MFMA16(F0, F1, F2, F3)                                                      \
    acc[F0][0] = __builtin_amdgcn_mfma_f32_16x16x32_bf16(a0, b0, acc[F0][0], 0,0,0); \
    acc[F0][1] = __builtin_amdgcn_mfma_f32_16x16x32_bf16(a0, b1, acc[F0][1], 0,0,0); \
    acc[F0][2] = __builtin_amdgcn_mfma_f32_16x16x32_bf16(a0, b2, acc[F0][2], 0,0,0); \
    acc[F0][3] = __builtin_amdgcn_mfma_f32_16x16x32_bf16(a0, b3, acc[F0][3], 0,0,0); \
    acc[F1][0] = __builtin_amdgcn_mfma_f32_16x16x32_bf16(a1, b0, acc[F1][0], 0,0,0); \
    acc[F1][1] = __builtin_amdgcn_mfma_f32_16x16x32_bf16(a1, b1, acc[F1][1], 0,0,0); \
    acc[F1][2] = __builtin_amdgcn_mfma_f32_16x16x32_bf16(a1, b2, acc[F1][2], 0,0,0); \
    acc[F1][3] = __builtin_amdgcn_mfma_f32_16x16x32_bf16(a1, b3, acc[F1][3], 0,0,0); \
    acc[F2][0] = __builtin_amdgcn_mfma_f32_16x16x32_bf16(a2, b0, acc[F2][0], 0,0,0); \
    acc[F2][1] = __builtin_amdgcn_mfma_f32_16x16x32_bf16(a2, b1, acc[F2][1], 0,0,0); \
    acc[F2][2] = __builtin_amdgcn_mfma_f32_16x16x32_bf16(a2, b2, acc[F2][2], 0,0,0); \
    acc[F2][3] = __builtin_amdgcn_mfma_f32_16x16x32_bf16(a2, b3, acc[F2][3], 0,0,0); \
    acc[F3][0] = __builtin_amdgcn_mfma_f32_16x16x32_bf16(a3, b0, acc[F3][0], 0,0,0); \
    acc[F3][1] = __builtin_amdgcn_mfma_f32_16x16x32_bf16(a3, b1, acc[F3][1], 0,0,0); \
    acc[F3][2] = __builtin_amdgcn_mfma_f32_16x16x32_bf16(a3, b2, acc[F3][2], 0,0,0); \
    acc[F3][3] = __builtin_amdgcn_mfma_f32_16x16x32_bf16(a3, b3, acc[F3][3], 0,0,0);

#define PHASE_SYNC()                                           \
    __builtin_amdgcn_s_barrier();                              \
    asm volatile("s_waitcnt lgkmcnt(0)" ::: "memory");         \
    __builtin_amdgcn_sched_barrier(0);

template<int RELU>
__global__ __launch_bounds__(512, 1)
void gemm_mfma256(const bf16_t* __restrict__ A, const bf16_t* __restrict__ W,
                  const float* __restrict__ ba, const float* __restrict__ bb,
                  const float* __restrict__ bc, const float* __restrict__ bd,
                  unsigned short* __restrict__ Cb, int M, int N, int K)
{
    __shared__ __align__(16) bf16_t As[2][256 * 64];
    __shared__ __align__(16) bf16_t Bs[2][256 * 64];

    const int tid  = threadIdx.x;
    const int wid  = tid >> 6;        // 0..7
    const int lane = tid & 63;
    const int lo   = lane & 15;
    const int hi   = lane >> 4;

    // XCD-aware 2D-chunk swizzle: xcd = id&7 owns an (8 x GY/2) block chunk.
    const int GY = gridDim.y;
    const int id = blockIdx.y * gridDim.x + blockIdx.x;
    const int xcd = id & 7;
    const int c   = id >> 3;                  // 0 .. 8*(GY/2)-1
    const int CN  = GY >> 1;
    const int m_idx = ((xcd & 3) << 3) + (c & 7);
    const int n_idx = (xcd >> 2) * CN + (c >> 3);
    const int m0 = m_idx * 256;
    const int n0 = n_idx * 256;

    const int wm = (wid & 1) * 128;   // wave M offset
    const int wn = (wid >> 1) * 64;   // wave N offset

    const int srow = tid >> 3;                           // 0..63
    const int ssk  = (((tid & 7) ^ (srow & 7)) * 8);     // pre-swizzled source
    const bf16_t* pa = A + (size_t)(m0 + srow) * K + ssk;
    const bf16_t* pb = W + (size_t)(n0 + srow) * K + ssk;
    const int lbase = (wid << 3) * 64;

    auto stageA = [&](int buf, int koff) {
        #pragma unroll
        for (int i = 0; i < 4; ++i)
            gld16(pa + (size_t)i * 64 * K + koff, &As[buf][i * 64 * 64 + lbase]);
    };
    auto stageB = [&](int buf, int koff) {
        #pragma unroll
        for (int i = 0; i < 4; ++i)
            gld16(pb + (size_t)i * 64 * K + koff, &Bs[buf][i * 64 * 64 + lbase]);
    };

    auto ldA = [&](int buf, int f, int cc) -> bf16x8 {
        const int row = wm + f * 16 + lo;
        const int ch  = ((cc * 4 + hi) ^ (lo & 7)) * 8;
        return *(const bf16x8*)&As[buf][row * 64 + ch];
    };
    auto ldB = [&](int buf, int g, int cc) -> bf16x8 {
        const int row = wn + g * 16 + lo;
        const int ch  = ((cc * 4 + hi) ^ (lo & 7)) * 8;
        return *(const bf16x8*)&Bs[buf][row * 64 + ch];
    };

    f32x4 acc[8][4];
    #pragma unroll
    for (int f = 0; f < 8; ++f)
        #pragma unroll
        for (int g = 0; g < 4; ++g) acc[f][g] = (f32x4){0.f, 0.f, 0.f, 0.f};

    // prologue: stage tile 0 into buf 0, full drain
    stageA(0, 0);
    stageB(0, 0);
    asm volatile("s_waitcnt vmcnt(0)" ::: "memory");
    __builtin_amdgcn_s_barrier();

    const int nt = K >> 6;
    for (int t = 0; t < nt; ++t) {
        const int buf = t & 1;
        const int knext = (t + 1) << 6;
        const bool pf = (t + 1 < nt);
        bf16x8 a0, a1, a2, a3, b0, b1, b2, b3;

        // ---- phase 0: (k-chunk 0, M-half 0); issue A-prefetch ----
        a0 = ldA(buf, 0, 0); a1 = ldA(buf, 1, 0); a2 = ldA(buf, 2, 0); a3 = ldA(buf, 3, 0);
        b0 = ldB(buf, 0, 0); b1 = ldB(buf, 1, 0); b2 = ldB(buf, 2, 0); b3 = ldB(buf, 3, 0);
        if (pf) stageA(buf ^ 1, knext);
        PHASE_SYNC();
        __builtin_amdgcn_s_setprio(1);
        MFMA16(0, 1, 2, 3);
        __builtin_amdgcn_s_setprio(0);
        __builtin_amdgcn_s_barrier();

        // ---- phase 1: (k-chunk 0, M-half 1), reuse b0-b3; issue B-prefetch ----
        a0 = ldA(buf, 4, 0); a1 = ldA(buf, 5, 0); a2 = ldA(buf, 6, 0); a3 = ldA(buf, 7, 0);
        if (pf) stageB(buf ^ 1, knext);
        PHASE_SYNC();
        __builtin_amdgcn_s_setprio(1);
        MFMA16(4, 5, 6, 7);
        __builtin_amdgcn_s_setprio(0);
        __builtin_amdgcn_s_barrier();

        // ---- phase 2: (k-chunk 1, M-half 0) ----
        a0 = ldA(buf, 0, 1); a1 = ldA(buf, 1, 1); a2 = ldA(buf, 2, 1); a3 = ldA(buf, 3, 1);
        b0 = ldB(buf, 0, 1); b1 = ldB(buf, 1, 1); b2 = ldB(buf, 2, 1); b3 = ldB(buf, 3, 1);
        PHASE_SYNC();
        __builtin_amdgcn_s_setprio(1);
        MFMA16(0, 1, 2, 3);
        __builtin_amdgcn_s_setprio(0);
        __builtin_amdgcn_s_barrier();

        // ---- phase 3: (k-chunk 1, M-half 1), reuse b0-b3 ----
        a0 = ldA(buf, 4, 1); a1 = ldA(buf, 5, 1); a2 = ldA(buf, 6, 1); a3 = ldA(buf, 7, 1);
        PHASE_SYNC();
        __builtin_amdgcn_s_setprio(1);
        MFMA16(4, 5, 6, 7);
        __builtin_amdgcn_s_setprio(0);
        // tile boundary: own prefetch must land; barrier makes it collective
        asm volatile("s_waitcnt vmcnt(0)" ::: "memory");
        __builtin_amdgcn_s_barrier();
    }

    // epilogue
    const int seg = n0 >> 10;
    const float* bias = (seg == 0) ? ba : (seg == 1) ? bb : (seg == 2) ? bc : bd;
    const int nl = (n0 & 1023);
    float bv[4];
    #pragma unroll
    for (int g = 0; g < 4; ++g) bv[g] = bias[nl + wn + g * 16 + lo];
    #pragma unroll
    for (int f = 0; f < 8; ++f)
        #pragma unroll
        for (int g = 0; g < 4; ++g)
            #pragma unroll
            for (int r = 0; r < 4; ++r) {
                float v = acc[f][g][r] + bv[g];
                if (RELU) v = fmaxf(v, 0.f);
                Cb[(size_t)(m0 + wm + f * 16 + hi * 4 + r) * N
                   + (n0 + wn + g * 16 + lo)] = f2bf(v);
            }
}

// ---------------------------------------------------------------------------
// MFMA attention v2 (unchanged round 8): one block per (head,batch), 8 waves,
// K/V fetched once, swizzled LDS, async-STAGE split.
// ---------------------------------------------------------------------------
template<int HAS_MASK>
__global__ __launch_bounds__(512, 2)
void attn_mfma(const bf16_t* __restrict__ Q, const bf16_t* __restrict__ K,
               const bf16_t* __restrict__ V, int qstride, int kvstride,
               const int* __restrict__ mask,
               unsigned short* __restrict__ O, int Lk)
{
    __shared__ __align__(16) unsigned short Ks[64][72];    // [k][d] swz
    __shared__ __align__(16) unsigned short Vt[64][72];    // [d][k] swz
    __shared__ __align__(16) unsigned short Ps[128][72];   // [q][k] linear
    __shared__ int smask[64];

    const int tid  = threadIdx.x;
    const int wid  = tid >> 6;
    const int lane = tid & 63;
    const int lo   = lane & 15;
    const int hi   = lane >> 4;
    const int h    = blockIdx.x;
    const int b    = blockIdx.y;
    const int Lq   = 512;

    bf16x8 qf[4][2];
    #pragma unroll
    for (int s4 = 0; s4 < 4; ++s4) {
        const bf16_t* qp = Q + (size_t)(b*Lq + s4*128 + wid*16 + lo) * qstride
                             + h*DHEAD + hi*8;
        qf[s4][0] = *(const bf16x8*)qp;
        qf[s4][1] = *(const bf16x8*)(qp + 32);
    }

    float mrun[4][4], lrun[4][4];
    f32x4 Oc[4][4];
    #pragma unroll
    for (int s4 = 0; s4 < 4; ++s4)
        #pragma unroll
        for (int r = 0; r < 4; ++r) {
            mrun[s4][r] = -INFINITY; lrun[s4][r] = 0.f;
            Oc[s4][r] = (f32x4){0.f, 0.f, 0.f, 0.f};
        }

    ushort8 r0, r1;
    int mreg = 0;

    auto load_tile = [&](int k0) {
        if (tid < 256) {
            const int sr = tid >> 2, sc = (tid & 3) * 16;
            const unsigned short* kp = (const unsigned short*)
                (K + (size_t)(b*Lk + k0 + sr) * kvstride + h*DHEAD + sc);
            r0 = *(const ushort8*)kp;
            r1 = *(const ushort8*)(kp + 8);
        } else {
            const int t2 = tid - 256, sr = t2 >> 2, sc = (t2 & 3) * 16;
            const unsigned short* vp = (const unsigned short*)
                (V + (size_t)(b*Lk + k0 + sr) * kvstride + h*DHEAD + sc);
            r0 = *(const ushort8*)vp;
            r1 = *(const ushort8*)(vp + 8);
        }
        if (HAS_MASK && tid < 64) mreg = mask[b*Lk + k0 + tid];
    };
    auto store_tile = [&]() {
        if (tid < 256) {
            const int sr = tid >> 2, sc = (tid & 3) * 16;
            const int x = ((sr >> 3) & 7) << 3;
            *(ushort8*)&Ks[sr][sc ^ x]       = r0;
            *(ushort8*)&Ks[sr][(sc + 8) ^ x] = r1;
        } else {
            const int t2 = tid - 256, sr = t2 >> 2, sc = (t2 & 3) * 16;
            #pragma unroll
            for (int t = 0; t < 8; ++t) {
                const int d0 = sc + t, d1 = sc + 8 + t;
                Vt[d0][sr ^ (((d0 >> 3) & 7) << 3)] = r0[t];
                Vt[d1][sr ^ (((d1 >> 3) & 7) << 3)] = r1[t];
            }
        }
        if (HAS_MASK && tid < 64) smask[tid] = mreg;
    };

    load_tile(0);
    store_tile();
    __syncthreads();

    int k0 = 0;
    while (true) {
        const bool more = (k0 + 64 < Lk);
        if (more) load_tile(k0 + 64);

        #pragma unroll
        for (int s4 = 0; s4 < 4; ++s4) {
            f32x4 sv[4];
            #pragma unroll
            for (int j = 0; j < 4; ++j) sv[j] = (f32x4){0.f, 0.f, 0.f, 0.f};
            #pragma unroll
            for (int kk = 0; kk < 2; ++kk) {
                #pragma unroll
                for (int j = 0; j < 4; ++j) {
                    const int krow = j*16 + lo;
                    const int kcol = (kk*32 + hi*8) ^ (((krow >> 3) & 7) << 3);
                    bf16x8 bfrag = *(const bf16x8*)&Ks[krow][kcol];
                    sv[j] = __builtin_amdgcn_mfma_f32_16x16x32_bf16(
                        qf[s4][kk], bfrag, sv[j], 0, 0, 0);
                }
            }
            #pragma unroll
            for (int j = 0; j < 4; ++j) {
                bool msk = HAS_MASK ? (smask[j*16 + lo] != 0) : false;
                #pragma unroll
                for (int r = 0; r < 4; ++r) {
                    float x = sv[j][r] * 0.125f;
                    sv[j][r] = msk ? NEGV : x;
                }
            }
            #pragma unroll
            for (int r = 0; r < 4; ++r) {
                float tm = fmaxf(fmaxf(sv[0][r], sv[1][r]), fmaxf(sv[2][r], sv[3][r]));
                #pragma unroll
                for (int m = 1; m < 16; m <<= 1) tm = fmaxf(tm, __shfl_xor(tm, m));
                float mnew = fmaxf(mrun[s4][r], tm);
                float f = __expf(mrun[s4][r] - mnew);
                float ps = 0.f;
                #pragma unroll
                for (int j = 0; j < 4; ++j) {
                    float p = __expf(sv[j][r] - mnew);
                    sv[j][r] = p;
                    ps += p;
                }
                #pragma unroll
                for (int m = 1; m < 16; m <<= 1) ps += __shfl_xor(ps, m);
                lrun[s4][r] = lrun[s4][r] * f + ps;
                mrun[s4][r] = mnew;
                #pragma unroll
                for (int n = 0; n < 4; ++n) Oc[s4][n][r] *= f;
                #pragma unroll
                for (int j = 0; j < 4; ++j)
                    Ps[wid*16 + hi*4 + r][j*16 + lo] = f2bf(sv[j][r]);
            }
            #pragma unroll
            for (int kk = 0; kk < 2; ++kk) {
                bf16x8 pa = *(const bf16x8*)&Ps[wid*16 + lo][kk*32 + hi*8];
                #pragma unroll
                for (int n = 0; n < 4; ++n) {
                    const int vrow = n*16 + lo;
                    const int vcol = (kk*32 + hi*8) ^ (((vrow >> 3) & 7) << 3);
                    bf16x8 vf = *(const bf16x8*)&Vt[vrow][vcol];
                    Oc[s4][n] = __builtin_amdgcn_mfma_f32_16x16x32_bf16(
                        pa, vf, Oc[s4][n], 0, 0, 0);
                }
            }
        }

        if (!more) break;
        __syncthreads();
        store_tile();
        __syncthreads();
        k0 += 64;
    }

    #pragma unroll
    for (int s4 = 0; s4 < 4; ++s4)
        #pragma unroll
        for (int r = 0; r < 4; ++r) {
            float inv = 1.f / lrun[s4][r];
            const size_t row = (size_t)(b*Lq + s4*128 + wid*16 + hi*4 + r) * HIDN
                             + h*DHEAD;
            #pragma unroll
            for (int n = 0; n < 4; ++n)
                O[row + n*16 + lo] = f2bf(Oc[s4][n][r] * inv);
        }
}

// ---------------------------------------------------------------------------
// LayerNorm(X + R): X,R bf16; stats fp32; write bf16 (in-place ok) and/or f32.
// ---------------------------------------------------------------------------
template<int WF32, int WBF>
__global__ __launch_bounds__(256)
void ln_res_b(const unsigned short* __restrict__ X, const unsigned short* __restrict__ R,
              const float* __restrict__ G, const float* __restrict__ Bv,
              unsigned short* __restrict__ OutB, float* __restrict__ OutF)
{
    const int row = blockIdx.x;
    const int tid = threadIdx.x;
    const size_t base = (size_t)row * HIDN + tid * 4;
    ushort4v xv = *(const ushort4v*)(X + base);
    ushort4v rv = *(const ushort4v*)(R + base);
    float y[4];
    #pragma unroll
    for (int t = 0; t < 4; ++t) y[t] = bf2f(xv[t]) + bf2f(rv[t]);
    float s1 = y[0] + y[1] + y[2] + y[3];
    float s2 = y[0]*y[0] + y[1]*y[1] + y[2]*y[2] + y[3]*y[3];
    #pragma unroll
    for (int m = 1; m < 64; m <<= 1) {
        s1 += __shfl_xor(s1, m);
        s2 += __shfl_xor(s2, m);
    }
    __shared__ float red1[4], red2[4];
    const int wave = tid >> 6, lane = tid & 63;
    if (lane == 0) { red1[wave] = s1; red2[wave] = s2; }
    __syncthreads();
    s1 = red1[0] + red1[1] + red1[2] + red1[3];
    s2 = red2[0] + red2[1] + red2[2] + red2[3];
    const float mean = s1 * (1.f / HIDN);
    const float var  = s2 * (1.f / HIDN) - mean * mean;
    const float inv  = rsqrtf(var + LN_EPS);
    float4 gv = *(const float4*)(G + tid*4);
    float4 bv = *(const float4*)(Bv + tid*4);
    float o[4];
    o[0] = gv.x * (y[0]-mean) * inv + bv.x;
    o[1] = gv.y * (y[1]-mean) * inv + bv.y;
    o[2] = gv.z * (y[2]-mean) * inv + bv.z;
    o[3] = gv.w * (y[3]-mean) * inv + bv.w;
    if (WBF) {
        ushort4v ob;
        #pragma unroll
        for (int t = 0; t < 4; ++t) ob[t] = f2bf(o[t]);
        *(ushort4v*)(OutB + base) = ob;
    }
    if (WF32) {
        float4 of = {o[0], o[1], o[2], o[3]};
        *(float4*)(OutF + base) = of;
    }
}

// ---------------------------------------------------------------------------
// One-shot fp32 -> bf16 conversion of 1Mi-element units (weights + acts).
// ---------------------------------------------------------------------------
struct CvtArgs {
    const float* src[32];
    unsigned short* dst[32];
};

__global__ __launch_bounds__(256)
void cvt_units(CvtArgs args)
{
    const float* s = args.src[blockIdx.y];
    unsigned short* d = args.dst[blockIdx.y];
    const int i = blockIdx.x * 256 + threadIdx.x;   // 0..131071
    const float4* p = (const float4*)s + (size_t)i * 2;
    float4 a = p[0], b = p[1];
    ushort8 o;
    o[0] = f2bf(a.x); o[1] = f2bf(a.y); o[2] = f2bf(a.z); o[3] = f2bf(a.w);
    o[4] = f2bf(b.x); o[5] = f2bf(b.y); o[6] = f2bf(b.z); o[7] = f2bf(b.w);
    ((ushort8*)d)[i] = o;
}

// ---------------------------------------------------------------------------
extern "C" void kernel_launch(void* const* d_in, const int* in_sizes, int n_in,
                              void* d_out, int out_size, void* d_ws, size_t ws_size,
                              hipStream_t stream)
{
    const float* img   = (const float*)d_in[0];
    const float* ques  = (const float*)d_in[1];
    const float* kg    = (const float*)d_in[2];
    const int*   qmask = (const int*)d_in[3];
    const int*   kmask = (const int*)d_in[4];
    const float* qw = (const float*)d_in[5];
    const float* qb = (const float*)d_in[6];
    const float* kw = (const float*)d_in[7];
    const float* kb = (const float*)d_in[8];
    const float* vw = (const float*)d_in[9];
    const float* vb = (const float*)d_in[10];
    const float* ow = (const float*)d_in[11];
    const float* ob = (const float*)d_in[12];
    const float* w1 = (const float*)d_in[13];
    const float* b1 = (const float*)d_in[14];
    const float* w2 = (const float*)d_in[15];
    const float* b2 = (const float*)d_in[16];
    const float* lng = (const float*)d_in[17];
    const float* lnb = (const float*)d_in[18];
    float* out = (float*)d_out;

    const int B = 16;
    const int NX = B * 512;                    // 8192 rows
    const size_t WSTEP = (size_t)1024 * 1024;
    const size_t MB = (size_t)1 << 20;
    const size_t MELEM = (size_t)1024 * 1024;

    char* wsb = (char*)d_ws;
    unsigned short* xb    = (unsigned short*)(wsb);            // 16 MB
    unsigned short* bM    = (unsigned short*)(wsb + 16*MB);    // 16 MB
    unsigned short* bOb   = (unsigned short*)(wsb + 32*MB);    // 16 MB
    unsigned short* quesb = (unsigned short*)(wsb + 48*MB);    //  2 MB
    unsigned short* kgb   = (unsigned short*)(wsb + 50*MB);    //  4 MB
    unsigned short* wa    = (unsigned short*)(wsb + 56*MB);    // 40 MB weight arena
    unsigned short* bQKV  = (unsigned short*)(wsb + 96*MB);    // 48 MB
    unsigned short* bKV   = (unsigned short*)(wsb + 144*MB);   //  8 MB
    unsigned short* hb    = (unsigned short*)(wsb + 96*MB);    // 64 MB, overlays bQKV/bKV

    CvtArgs ca;
    int u = 0;
    auto addu = [&](const float* src, int melems, unsigned short* dst) {
        for (int i = 0; i < melems; ++i) {
            ca.src[u] = src + (size_t)i * MELEM;
            ca.dst[u] = dst + (size_t)i * MELEM;
            ++u;
        }
    };
    addu(qw + 0*WSTEP, 1, wa + 0*MELEM);
    addu(kw + 0*WSTEP, 1, wa + 1*MELEM);
    addu(vw + 0*WSTEP, 1, wa + 2*MELEM);
    addu(qw + 1*WSTEP, 1, wa + 3*MELEM);
    addu(kw + 1*WSTEP, 1, wa + 4*MELEM);
    addu(vw + 1*WSTEP, 1, wa + 5*MELEM);
    addu(qw + 2*WSTEP, 1, wa + 6*MELEM);
    addu(kw + 2*WSTEP, 1, wa + 7*MELEM);
    addu(vw + 2*WSTEP, 1, wa + 8*MELEM);
    addu(ow + 0*WSTEP, 1, wa + 9*MELEM);
    addu(ow + 1*WSTEP, 1, wa + 10*MELEM);
    addu(ow + 2*WSTEP, 1, wa + 11*MELEM);
    addu(w1, 4, wa + 12*MELEM);
    addu(w2, 4, wa + 16*MELEM);
    addu(img,  8, xb);
    addu(ques, 1, quesb);
    addu(kg,   2, kgb);

    dim3 blk(256);
    cvt_units<<<dim3(512, u), blk, 0, stream>>>(ca);

    auto gemm = [&](const unsigned short* A, const unsigned short* W,
                    const float* ba, const float* bb_, const float* bc, const float* bd,
                    unsigned short* C, int M, int N, int K, int relu) {
        // 256^2 8-phase kernel for the big shapes
        if (N >= 3072 && (M % 256) == 0 && (N % 256) == 0
            && ((M / 256) % 8) == 0 && ((N / 256) % 2) == 0) {
            dim3 grid(M / 256, N / 256);
            if (relu) gemm_mfma256<1><<<grid, dim3(512), 0, stream>>>(
                (const bf16_t*)A, (const bf16_t*)W, ba, bb_, bc, bd, C, M, N, K);
            else      gemm_mfma256<0><<<grid, dim3(512), 0, stream>>>(
                (const bf16_t*)A, (const bf16_t*)W, ba, bb_, bc, bd, C, M, N, K);
            return;
        }
        dim3 grid(M / 128, N / 128);
        if (relu) gemm_mfma<1><<<grid, blk, 0, stream>>>(
            (const bf16_t*)A, (const bf16_t*)W, ba, bb_, bc, bd, C, M, N, K);
        else      gemm_mfma<0><<<grid, blk, 0, stream>>>(
            (const bf16_t*)A, (const bf16_t*)W, ba, bb_, bc, bd, C, M, N, K);
    };

    const unsigned short* Akv[3] = {xb, quesb, kgb};
    const int Mkv[3] = {NX, B * 64, B * 128};
    const int Lk[3]  = {512, 64, 128};

    dim3 ablk(512);
    dim3 agrid(NHEADS, B);

    for (int t = 0; t < 3; ++t) {
        if (t == 0) {
            gemm(xb, wa + 0*MELEM, qb + 0, kb + 0, vb + 0, vb + 0,
                 bQKV, NX, 3072, 1024, 0);
            attn_mfma<0><<<agrid, ablk, 0, stream>>>(
                (const bf16_t*)bQKV, (const bf16_t*)bQKV + 1024, (const bf16_t*)bQKV + 2048,
                3072, 3072, nullptr, bOb, Lk[t]);
        } else {
            gemm(xb, wa + (t == 1 ? 3 : 6)*MELEM,
                 qb + t*1024, qb + t*1024, qb + t*1024, qb + t*1024,
                 bQKV, NX, 1024, 1024, 0);
            gemm(Akv[t], wa + (t == 1 ? 4 : 7)*MELEM,
                 kb + t*1024, vb + t*1024, vb + t*1024, vb + t*1024,
                 bKV, Mkv[t], 2048, 1024, 0);
            attn_mfma<1><<<agrid, ablk, 0, stream>>>(
                (const bf16_t*)bQKV, (const bf16_t*)bKV, (const bf16_t*)bKV + 1024,
                1024, 2048, (t == 1 ? qmask : kmask), bOb, Lk[t]);
        }
        gemm(bOb, wa + (9 + t)*MELEM,
             ob + t*1024, ob + t*1024, ob + t*1024, ob + t*1024,
             bM, NX, 1024, 1024, 0);
        ln_res_b<0,1><<<NX, blk, 0, stream>>>(xb, bM, lng + t*1024, lnb + t*1024, xb, nullptr);
    }

    // FFN
    gemm(xb, wa + 12*MELEM, b1, b1 + 1024, b1 + 2048, b1 + 3072, hb, NX, FFD, 1024, 1);
    gemm(hb, wa + 16*MELEM, b2, b2, b2, b2, bM, NX, 1024, 4096, 0);
    ln_res_b<1,0><<<NX, blk, 0, stream>>>(xb, bM, lng + 3*1024, lnb + 3*1024, nullptr, out);
}

// Round 11
// 513.458 us; speedup vs baseline: 1.1298x; 1.0060x over previous
//
#include <hip/hip_runtime.h>
#include <math.h>

#define HIDN 1024
#define NHEADS 16
#define DHEAD 64
#define FFD 4096
#define LN_EPS 1e-6f
#define NEGV -1e9f

typedef __bf16 bf16_t;
typedef __bf16 bf16x8 __attribute__((ext_vector_type(8)));
typedef float f32x4 __attribute__((ext_vector_type(4)));
typedef unsigned short ushort8 __attribute__((ext_vector_type(8)));
typedef unsigned short ushort4v __attribute__((ext_vector_type(4)));

__device__ __forceinline__ unsigned short f2bf(float f) {
    unsigned u = __float_as_uint(f);
    return (unsigned short)((u + 0x7FFFu + ((u >> 16) & 1u)) >> 16);
}
__device__ __forceinline__ float bf2f(unsigned short u) {
    return __uint_as_float((unsigned)u << 16);
}
__device__ __forceinline__ void gld16(const void* g, void* l) {
    __builtin_amdgcn_global_load_lds(
        (const __attribute__((address_space(1))) void*)g,
        (__attribute__((address_space(3))) void*)l, 16, 0, 0);
}

// ---------------------------------------------------------------------------
// 128^2 bf16 MFMA GEMM (proven rounds 6-8): BK=64, 4 waves, T2 swizzle,
// double-buffered LDS with issue-early staging. Used for N<=2048 shapes.
// ---------------------------------------------------------------------------
template<int RELU>
__global__ __launch_bounds__(256)
void gemm_mfma(const bf16_t* __restrict__ A, const bf16_t* __restrict__ W,
               const float* __restrict__ ba, const float* __restrict__ bb,
               const float* __restrict__ bc, const float* __restrict__ bd,
               unsigned short* __restrict__ Cb, int M, int N, int K)
{
    __shared__ __align__(16) bf16_t As[2][128 * 64];
    __shared__ __align__(16) bf16_t Bs[2][128 * 64];

    const int tid  = threadIdx.x;
    const int wid  = tid >> 6;
    const int lane = tid & 63;
    const int m0 = blockIdx.x * 128;
    const int n0 = blockIdx.y * 128;
    const int wm = (wid & 1) * 64;
    const int wn = (wid >> 1) * 64;

    const int sr = (wid << 3) + (lane >> 3);            // 0..31
    const int sk = (((lane & 7) ^ (lane >> 3)) * 8);
    const bf16_t* pa = A + (size_t)(m0 + sr) * K + sk;
    const bf16_t* pb = W + (size_t)(n0 + sr) * K + sk;
    const int lofs = (wid << 3) * 64;

    const int lr  = lane & 15;
    const int hi_ = lane >> 4;
    const int ch0 = ((hi_ + 0) ^ (lane & 7)) * 8;   // kk = 0
    const int ch1 = ((hi_ + 4) ^ (lane & 7)) * 8;   // kk = 32

    f32x4 acc[4][4];
    #pragma unroll
    for (int i = 0; i < 4; ++i)
        #pragma unroll
        for (int j = 0; j < 4; ++j) acc[i][j] = (f32x4){0.f, 0.f, 0.f, 0.f};

    auto stage = [&](int buf, int koff) {
        #pragma unroll
        for (int c = 0; c < 4; ++c) {
            gld16(pa + (size_t)c * 32 * K + koff, &As[buf][lofs + c * 32 * 64]);
            gld16(pb + (size_t)c * 32 * K + koff, &Bs[buf][lofs + c * 32 * 64]);
        }
    };
    auto compute = [&](int buf) {
        const bf16_t* fa = &As[buf][(wm + lr) * 64];
        const bf16_t* fb = &Bs[buf][(wn + lr) * 64];
        #pragma unroll
        for (int kk = 0; kk < 2; ++kk) {
            const int ch = kk ? ch1 : ch0;
            bf16x8 a[4], b[4];
            #pragma unroll
            for (int i = 0; i < 4; ++i) {
                a[i] = *(const bf16x8*)(fa + i * 16 * 64 + ch);
                b[i] = *(const bf16x8*)(fb + i * 16 * 64 + ch);
            }
            #pragma unroll
            for (int i = 0; i < 4; ++i)
                #pragma unroll
                for (int j = 0; j < 4; ++j)
                    acc[i][j] = __builtin_amdgcn_mfma_f32_16x16x32_bf16(
                        a[i], b[j], acc[i][j], 0, 0, 0);
        }
    };

    stage(0, 0);
    asm volatile("s_waitcnt vmcnt(0)" ::: "memory");
    __syncthreads();

    for (int k0 = 0; k0 < K; k0 += 128) {
        if (k0 + 64 < K) stage(1, k0 + 64);
        compute(0);
        asm volatile("s_waitcnt vmcnt(0)" ::: "memory");
        __syncthreads();
        if (k0 + 128 < K) stage(0, k0 + 128);
        compute(1);
        asm volatile("s_waitcnt vmcnt(0)" ::: "memory");
        __syncthreads();
    }

    const int seg = n0 >> 10;
    const float* bias = (seg == 0) ? ba : (seg == 1) ? bb : (seg == 2) ? bc : bd;
    const int nl = (n0 & 1023);
    const int er = wm + (lane >> 4) * 4;
    const int ec = wn + (lane & 15);
    float bv[4];
    #pragma unroll
    for (int j = 0; j < 4; ++j) bv[j] = bias[nl + ec + j * 16];
    #pragma unroll
    for (int i = 0; i < 4; ++i)
        #pragma unroll
        for (int j = 0; j < 4; ++j)
            #pragma unroll
            for (int r = 0; r < 4; ++r) {
                float v = acc[i][j][r] + bv[j];
                if (RELU) v = fmaxf(v, 0.f);
                Cb[(size_t)(m0 + er + i * 16 + r) * N + (n0 + ec + j * 16)] = f2bf(v);
            }
}

// ---------------------------------------------------------------------------
// 256^2 bf16 MFMA GEMM, round 11: same PROVEN 2-barrier dbuf structure as the
// 128^2 kernel (compiler fine-schedules 24 ds_reads + 64 MFMAs per wave per
// K-tile -> intra-wave LDS/MFMA overlap), but 256^2 tile amortizes the
// per-tile vmcnt(0)+barrier over 4x the compute. Round 10's hand-phased
// 8-barrier schedule forced LDS/MFMA lockstep (MfmaUtil 35%) - removed.
// 8 waves (2M x 4N), per-wave 128x64 out, LDS 128 KB. T2 chunk-XOR swizzle.
// 2D XCD chunk swizzle (round 10, FETCH 135->49 MB). K%128==0.
// ---------------------------------------------------------------------------
template<int RELU>
__global__ __launch_bounds__(512, 1)
void gemm_mfma256(const bf16_t* __restrict__ A, const bf16_t* __restrict__ W,
                  const float* __restrict__ ba, const float* __restrict__ bb,
                  const float* __restrict__ bc, const float* __restrict__ bd,
                  unsigned short* __restrict__ Cb, int M, int N, int K)
{
    __shared__ __align__(16) bf16_t As[2][256 * 64];
    __shared__ __align__(16) bf16_t Bs[2][256 * 64];

    const int tid  = threadIdx.x;
    const int wid  = tid >> 6;        // 0..7
    const int lane = tid & 63;
    const int lo   = lane & 15;
    const int hi   = lane >> 4;

    // XCD-aware 2D-chunk swizzle: xcd = id&7 owns an (8 x GY/2) block chunk.
    const int GY = gridDim.y;
    const int id = blockIdx.y * gridDim.x + blockIdx.x;
    const int xcd = id & 7;
    const int c   = id >> 3;
    const int CN  = GY >> 1;
    const int m_idx = ((xcd & 3) << 3) + (c & 7);
    const int n_idx = (xcd >> 2) * CN + (c >> 3);
    const int m0 = m_idx * 256;
    const int n0 = n_idx * 256;

    const int wm = (wid & 1) * 128;   // wave M offset
    const int wn = (wid >> 1) * 64;   // wave N offset

    const int srow = tid >> 3;                           // 0..63
    const int ssk  = (((tid & 7) ^ (srow & 7)) * 8);     // pre-swizzled source
    const bf16_t* pa = A + (size_t)(m0 + srow) * K + ssk;
    const bf16_t* pb = W + (size_t)(n0 + srow) * K + ssk;
    const int lbase = (wid << 3) * 64;

    auto stage = [&](int buf, int koff) {
        #pragma unroll
        for (int i = 0; i < 4; ++i) {
            gld16(pa + (size_t)i * 64 * K + koff, &As[buf][i * 64 * 64 + lbase]);
            gld16(pb + (size_t)i * 64 * K + koff, &Bs[buf][i * 64 * 64 + lbase]);
        }
    };

    f32x4 acc[8][4];
    #pragma unroll
    for (int f = 0; f < 8; ++f)
        #pragma unroll
        for (int g = 0; g < 4; ++g) acc[f][g] = (f32x4){0.f, 0.f, 0.f, 0.f};

    auto compute = [&](int buf) {
        #pragma unroll
        for (int kk = 0; kk < 2; ++kk) {
            bf16x8 a[8], b[4];
            #pragma unroll
            for (int f = 0; f < 8; ++f) {
                const int row = wm + f * 16 + lo;
                const int ch  = ((kk * 4 + hi) ^ (lo & 7)) * 8;
                a[f] = *(const bf16x8*)&As[buf][row * 64 + ch];
            }
            #pragma unroll
            for (int g = 0; g < 4; ++g) {
                const int row = wn + g * 16 + lo;
                const int ch  = ((kk * 4 + hi) ^ (lo & 7)) * 8;
                b[g] = *(const bf16x8*)&Bs[buf][row * 64 + ch];
            }
            #pragma unroll
            for (int f = 0; f < 8; ++f)
                #pragma unroll
                for (int g = 0; g < 4; ++g)
                    acc[f][g] = __builtin_amdgcn_mfma_f32_16x16x32_bf16(
                        a[f], b[g], acc[f][g], 0, 0, 0);
        }
    };

    stage(0, 0);
    asm volatile("s_waitcnt vmcnt(0)" ::: "memory");
    __syncthreads();

    for (int k0 = 0; k0 < K; k0 += 128) {
        if (k0 + 64 < K) stage(1, k0 + 64);
        compute(0);
        asm volatile("s_waitcnt vmcnt(0)" ::: "memory");
        __syncthreads();
        if (k0 + 128 < K) stage(0, k0 + 128);
        compute(1);
        asm volatile("s_waitcnt vmcnt(0)" ::: "memory");
        __syncthreads();
    }

    // epilogue
    const int seg = n0 >> 10;
    const float* bias = (seg == 0) ? ba : (seg == 1) ? bb : (seg == 2) ? bc : bd;
    const int nl = (n0 & 1023);
    float bv[4];
    #pragma unroll
    for (int g = 0; g < 4; ++g) bv[g] = bias[nl + wn + g * 16 + lo];
    #pragma unroll
    for (int f = 0; f < 8; ++f)
        #pragma unroll
        for (int g = 0; g < 4; ++g)
            #pragma unroll
            for (int r = 0; r < 4; ++r) {
                float v = acc[f][g][r] + bv[g];
                if (RELU) v = fmaxf(v, 0.f);
                Cb[(size_t)(m0 + wm + f * 16 + hi * 4 + r) * N
                   + (n0 + wn + g * 16 + lo)] = f2bf(v);
            }
}

// ---------------------------------------------------------------------------
// MFMA attention v2 (unchanged round 8): one block per (head,batch), 8 waves,
// K/V fetched once, swizzled LDS, async-STAGE split.
// ---------------------------------------------------------------------------
template<int HAS_MASK>
__global__ __launch_bounds__(512, 2)
void attn_mfma(const bf16_t* __restrict__ Q, const bf16_t* __restrict__ K,
               const bf16_t* __restrict__ V, int qstride, int kvstride,
               const int* __restrict__ mask,
               unsigned short* __restrict__ O, int Lk)
{
    __shared__ __align__(16) unsigned short Ks[64][72];    // [k][d] swz
    __shared__ __align__(16) unsigned short Vt[64][72];    // [d][k] swz
    __shared__ __align__(16) unsigned short Ps[128][72];   // [q][k] linear
    __shared__ int smask[64];

    const int tid  = threadIdx.x;
    const int wid  = tid >> 6;
    const int lane = tid & 63;
    const int lo   = lane & 15;
    const int hi   = lane >> 4;
    const int h    = blockIdx.x;
    const int b    = blockIdx.y;
    const int Lq   = 512;

    bf16x8 qf[4][2];
    #pragma unroll
    for (int s4 = 0; s4 < 4; ++s4) {
        const bf16_t* qp = Q + (size_t)(b*Lq + s4*128 + wid*16 + lo) * qstride
                             + h*DHEAD + hi*8;
        qf[s4][0] = *(const bf16x8*)qp;
        qf[s4][1] = *(const bf16x8*)(qp + 32);
    }

    float mrun[4][4], lrun[4][4];
    f32x4 Oc[4][4];
    #pragma unroll
    for (int s4 = 0; s4 < 4; ++s4)
        #pragma unroll
        for (int r = 0; r < 4; ++r) {
            mrun[s4][r] = -INFINITY; lrun[s4][r] = 0.f;
            Oc[s4][r] = (f32x4){0.f, 0.f, 0.f, 0.f};
        }

    ushort8 r0, r1;
    int mreg = 0;

    auto load_tile = [&](int k0) {
        if (tid < 256) {
            const int sr = tid >> 2, sc = (tid & 3) * 16;
            const unsigned short* kp = (const unsigned short*)
                (K + (size_t)(b*Lk + k0 + sr) * kvstride + h*DHEAD + sc);
            r0 = *(const ushort8*)kp;
            r1 = *(const ushort8*)(kp + 8);
        } else {
            const int t2 = tid - 256, sr = t2 >> 2, sc = (t2 & 3) * 16;
            const unsigned short* vp = (const unsigned short*)
                (V + (size_t)(b*Lk + k0 + sr) * kvstride + h*DHEAD + sc);
            r0 = *(const ushort8*)vp;
            r1 = *(const ushort8*)(vp + 8);
        }
        if (HAS_MASK && tid < 64) mreg = mask[b*Lk + k0 + tid];
    };
    auto store_tile = [&]() {
        if (tid < 256) {
            const int sr = tid >> 2, sc = (tid & 3) * 16;
            const int x = ((sr >> 3) & 7) << 3;
            *(ushort8*)&Ks[sr][sc ^ x]       = r0;
            *(ushort8*)&Ks[sr][(sc + 8) ^ x] = r1;
        } else {
            const int t2 = tid - 256, sr = t2 >> 2, sc = (t2 & 3) * 16;
            #pragma unroll
            for (int t = 0; t < 8; ++t) {
                const int d0 = sc + t, d1 = sc + 8 + t;
                Vt[d0][sr ^ (((d0 >> 3) & 7) << 3)] = r0[t];
                Vt[d1][sr ^ (((d1 >> 3) & 7) << 3)] = r1[t];
            }
        }
        if (HAS_MASK && tid < 64) smask[tid] = mreg;
    };

    load_tile(0);
    store_tile();
    __syncthreads();

    int k0 = 0;
    while (true) {
        const bool more = (k0 + 64 < Lk);
        if (more) load_tile(k0 + 64);

        #pragma unroll
        for (int s4 = 0; s4 < 4; ++s4) {
            f32x4 sv[4];
            #pragma unroll
            for (int j = 0; j < 4; ++j) sv[j] = (f32x4){0.f, 0.f, 0.f, 0.f};
            #pragma unroll
            for (int kk = 0; kk < 2; ++kk) {
                #pragma unroll
                for (int j = 0; j < 4; ++j) {
                    const int krow = j*16 + lo;
                    const int kcol = (kk*32 + hi*8) ^ (((krow >> 3) & 7) << 3);
                    bf16x8 bfrag = *(const bf16x8*)&Ks[krow][kcol];
                    sv[j] = __builtin_amdgcn_mfma_f32_16x16x32_bf16(
                        qf[s4][kk], bfrag, sv[j], 0, 0, 0);
                }
            }
            #pragma unroll
            for (int j = 0; j < 4; ++j) {
                bool msk = HAS_MASK ? (smask[j*16 + lo] != 0) : false;
                #pragma unroll
                for (int r = 0; r < 4; ++r) {
                    float x = sv[j][r] * 0.125f;
                    sv[j][r] = msk ? NEGV : x;
                }
            }
            #pragma unroll
            for (int r = 0; r < 4; ++r) {
                float tm = fmaxf(fmaxf(sv[0][r], sv[1][r]), fmaxf(sv[2][r], sv[3][r]));
                #pragma unroll
                for (int m = 1; m < 16; m <<= 1) tm = fmaxf(tm, __shfl_xor(tm, m));
                float mnew = fmaxf(mrun[s4][r], tm);
                float f = __expf(mrun[s4][r] - mnew);
                float ps = 0.f;
                #pragma unroll
                for (int j = 0; j < 4; ++j) {
                    float p = __expf(sv[j][r] - mnew);
                    sv[j][r] = p;
                    ps += p;
                }
                #pragma unroll
                for (int m = 1; m < 16; m <<= 1) ps += __shfl_xor(ps, m);
                lrun[s4][r] = lrun[s4][r] * f + ps;
                mrun[s4][r] = mnew;
                #pragma unroll
                for (int n = 0; n < 4; ++n) Oc[s4][n][r] *= f;
                #pragma unroll
                for (int j = 0; j < 4; ++j)
                    Ps[wid*16 + hi*4 + r][j*16 + lo] = f2bf(sv[j][r]);
            }
            #pragma unroll
            for (int kk = 0; kk < 2; ++kk) {
                bf16x8 pa = *(const bf16x8*)&Ps[wid*16 + lo][kk*32 + hi*8];
                #pragma unroll
                for (int n = 0; n < 4; ++n) {
                    const int vrow = n*16 + lo;
                    const int vcol = (kk*32 + hi*8) ^ (((vrow >> 3) & 7) << 3);
                    bf16x8 vf = *(const bf16x8*)&Vt[vrow][vcol];
                    Oc[s4][n] = __builtin_amdgcn_mfma_f32_16x16x32_bf16(
                        pa, vf, Oc[s4][n], 0, 0, 0);
                }
            }
        }

        if (!more) break;
        __syncthreads();
        store_tile();
        __syncthreads();
        k0 += 64;
    }

    #pragma unroll
    for (int s4 = 0; s4 < 4; ++s4)
        #pragma unroll
        for (int r = 0; r < 4; ++r) {
            float inv = 1.f / lrun[s4][r];
            const size_t row = (size_t)(b*Lq + s4*128 + wid*16 + hi*4 + r) * HIDN
                             + h*DHEAD;
            #pragma unroll
            for (int n = 0; n < 4; ++n)
                O[row + n*16 + lo] = f2bf(Oc[s4][n][r] * inv);
        }
}

// ---------------------------------------------------------------------------
// LayerNorm(X + R): X,R bf16; stats fp32; write bf16 (in-place ok) and/or f32.
// ---------------------------------------------------------------------------
template<int WF32, int WBF>
__global__ __launch_bounds__(256)
void ln_res_b(const unsigned short* __restrict__ X, const unsigned short* __restrict__ R,
              const float* __restrict__ G, const float* __restrict__ Bv,
              unsigned short* __restrict__ OutB, float* __restrict__ OutF)
{
    const int row = blockIdx.x;
    const int tid = threadIdx.x;
    const size_t base = (size_t)row * HIDN + tid * 4;
    ushort4v xv = *(const ushort4v*)(X + base);
    ushort4v rv = *(const ushort4v*)(R + base);
    float y[4];
    #pragma unroll
    for (int t = 0; t < 4; ++t) y[t] = bf2f(xv[t]) + bf2f(rv[t]);
    float s1 = y[0] + y[1] + y[2] + y[3];
    float s2 = y[0]*y[0] + y[1]*y[1] + y[2]*y[2] + y[3]*y[3];
    #pragma unroll
    for (int m = 1; m < 64; m <<= 1) {
        s1 += __shfl_xor(s1, m);
        s2 += __shfl_xor(s2, m);
    }
    __shared__ float red1[4], red2[4];
    const int wave = tid >> 6, lane = tid & 63;
    if (lane == 0) { red1[wave] = s1; red2[wave] = s2; }
    __syncthreads();
    s1 = red1[0] + red1[1] + red1[2] + red1[3];
    s2 = red2[0] + red2[1] + red2[2] + red2[3];
    const float mean = s1 * (1.f / HIDN);
    const float var  = s2 * (1.f / HIDN) - mean * mean;
    const float inv  = rsqrtf(var + LN_EPS);
    float4 gv = *(const float4*)(G + tid*4);
    float4 bv = *(const float4*)(Bv + tid*4);
    float o[4];
    o[0] = gv.x * (y[0]-mean) * inv + bv.x;
    o[1] = gv.y * (y[1]-mean) * inv + bv.y;
    o[2] = gv.z * (y[2]-mean) * inv + bv.z;
    o[3] = gv.w * (y[3]-mean) * inv + bv.w;
    if (WBF) {
        ushort4v ob;
        #pragma unroll
        for (int t = 0; t < 4; ++t) ob[t] = f2bf(o[t]);
        *(ushort4v*)(OutB + base) = ob;
    }
    if (WF32) {
        float4 of = {o[0], o[1], o[2], o[3]};
        *(float4*)(OutF + base) = of;
    }
}

// ---------------------------------------------------------------------------
// One-shot fp32 -> bf16 conversion of 1Mi-element units (weights + acts).
// ---------------------------------------------------------------------------
struct CvtArgs {
    const float* src[32];
    unsigned short* dst[32];
};

__global__ __launch_bounds__(256)
void cvt_units(CvtArgs args)
{
    const float* s = args.src[blockIdx.y];
    unsigned short* d = args.dst[blockIdx.y];
    const int i = blockIdx.x * 256 + threadIdx.x;   // 0..131071
    const float4* p = (const float4*)s + (size_t)i * 2;
    float4 a = p[0], b = p[1];
    ushort8 o;
    o[0] = f2bf(a.x); o[1] = f2bf(a.y); o[2] = f2bf(a.z); o[3] = f2bf(a.w);
    o[4] = f2bf(b.x); o[5] = f2bf(b.y); o[6] = f2bf(b.z); o[7] = f2bf(b.w);
    ((ushort8*)d)[i] = o;
}

// ---------------------------------------------------------------------------
extern "C" void kernel_launch(void* const* d_in, const int* in_sizes, int n_in,
                              void* d_out, int out_size, void* d_ws, size_t ws_size,
                              hipStream_t stream)
{
    const float* img   = (const float*)d_in[0];
    const float* ques  = (const float*)d_in[1];
    const float* kg    = (const float*)d_in[2];
    const int*   qmask = (const int*)d_in[3];
    const int*   kmask = (const int*)d_in[4];
    const float* qw = (const float*)d_in[5];
    const float* qb = (const float*)d_in[6];
    const float* kw = (const float*)d_in[7];
    const float* kb = (const float*)d_in[8];
    const float* vw = (const float*)d_in[9];
    const float* vb = (const float*)d_in[10];
    const float* ow = (const float*)d_in[11];
    const float* ob = (const float*)d_in[12];
    const float* w1 = (const float*)d_in[13];
    const float* b1 = (const float*)d_in[14];
    const float* w2 = (const float*)d_in[15];
    const float* b2 = (const float*)d_in[16];
    const float* lng = (const float*)d_in[17];
    const float* lnb = (const float*)d_in[18];
    float* out = (float*)d_out;

    const int B = 16;
    const int NX = B * 512;                    // 8192 rows
    const size_t WSTEP = (size_t)1024 * 1024;
    const size_t MB = (size_t)1 << 20;
    const size_t MELEM = (size_t)1024 * 1024;

    char* wsb = (char*)d_ws;
    unsigned short* xb    = (unsigned short*)(wsb);            // 16 MB
    unsigned short* bM    = (unsigned short*)(wsb + 16*MB);    // 16 MB
    unsigned short* bOb   = (unsigned short*)(wsb + 32*MB);    // 16 MB
    unsigned short* quesb = (unsigned short*)(wsb + 48*MB);    //  2 MB
    unsigned short* kgb   = (unsigned short*)(wsb + 50*MB);    //  4 MB
    unsigned short* wa    = (unsigned short*)(wsb + 56*MB);    // 40 MB weight arena
    unsigned short* bQKV  = (unsigned short*)(wsb + 96*MB);    // 48 MB
    unsigned short* bKV   = (unsigned short*)(wsb + 144*MB);   //  8 MB
    unsigned short* hb    = (unsigned short*)(wsb + 96*MB);    // 64 MB, overlays bQKV/bKV

    CvtArgs ca;
    int u = 0;
    auto addu = [&](const float* src, int melems, unsigned short* dst) {
        for (int i = 0; i < melems; ++i) {
            ca.src[u] = src + (size_t)i * MELEM;
            ca.dst[u] = dst + (size_t)i * MELEM;
            ++u;
        }
    };
    addu(qw + 0*WSTEP, 1, wa + 0*MELEM);
    addu(kw + 0*WSTEP, 1, wa + 1*MELEM);
    addu(vw + 0*WSTEP, 1, wa + 2*MELEM);
    addu(qw + 1*WSTEP, 1, wa + 3*MELEM);
    addu(kw + 1*WSTEP, 1, wa + 4*MELEM);
    addu(vw + 1*WSTEP, 1, wa + 5*MELEM);
    addu(qw + 2*WSTEP, 1, wa + 6*MELEM);
    addu(kw + 2*WSTEP, 1, wa + 7*MELEM);
    addu(vw + 2*WSTEP, 1, wa + 8*MELEM);
    addu(ow + 0*WSTEP, 1, wa + 9*MELEM);
    addu(ow + 1*WSTEP, 1, wa + 10*MELEM);
    addu(ow + 2*WSTEP, 1, wa + 11*MELEM);
    addu(w1, 4, wa + 12*MELEM);
    addu(w2, 4, wa + 16*MELEM);
    addu(img,  8, xb);
    addu(ques, 1, quesb);
    addu(kg,   2, kgb);

    dim3 blk(256);
    cvt_units<<<dim3(512, u), blk, 0, stream>>>(ca);

    auto gemm = [&](const unsigned short* A, const unsigned short* W,
                    const float* ba, const float* bb_, const float* bc, const float* bd,
                    unsigned short* C, int M, int N, int K, int relu) {
        // 256^2 dbuf kernel for the big shapes
        if (N >= 3072 && (M % 256) == 0 && (N % 256) == 0
            && ((M / 256) % 8) == 0 && ((N / 256) % 2) == 0 && (K % 128) == 0) {
            dim3 grid(M / 256, N / 256);
            if (relu) gemm_mfma256<1><<<grid, dim3(512), 0, stream>>>(
                (const bf16_t*)A, (const bf16_t*)W, ba, bb_, bc, bd, C, M, N, K);
            else      gemm_mfma256<0><<<grid, dim3(512), 0, stream>>>(
                (const bf16_t*)A, (const bf16_t*)W, ba, bb_, bc, bd, C, M, N, K);
            return;
        }
        dim3 grid(M / 128, N / 128);
        if (relu) gemm_mfma<1><<<grid, blk, 0, stream>>>(
            (const bf16_t*)A, (const bf16_t*)W, ba, bb_, bc, bd, C, M, N, K);
        else      gemm_mfma<0><<<grid, blk, 0, stream>>>(
            (const bf16_t*)A, (const bf16_t*)W, ba, bb_, bc, bd, C, M, N, K);
    };

    const unsigned short* Akv[3] = {xb, quesb, kgb};
    const int Mkv[3] = {NX, B * 64, B * 128};
    const int Lk[3]  = {512, 64, 128};

    dim3 ablk(512);
    dim3 agrid(NHEADS, B);

    for (int t = 0; t < 3; ++t) {
        if (t == 0) {
            gemm(xb, wa + 0*MELEM, qb + 0, kb + 0, vb + 0, vb + 0,
                 bQKV, NX, 3072, 1024, 0);
            attn_mfma<0><<<agrid, ablk, 0, stream>>>(
                (const bf16_t*)bQKV, (const bf16_t*)bQKV + 1024, (const bf16_t*)bQKV + 2048,
                3072, 3072, nullptr, bOb, Lk[t]);
        } else {
            gemm(xb, wa + (t == 1 ? 3 : 6)*MELEM,
                 qb + t*1024, qb + t*1024, qb + t*1024, qb + t*1024,
                 bQKV, NX, 1024, 1024, 0);
            gemm(Akv[t], wa + (t == 1 ? 4 : 7)*MELEM,
                 kb + t*1024, vb + t*1024, vb + t*1024, vb + t*1024,
                 bKV, Mkv[t], 2048, 1024, 0);
            attn_mfma<1><<<agrid, ablk, 0, stream>>>(
                (const bf16_t*)bQKV, (const bf16_t*)bKV, (const bf16_t*)bKV + 1024,
                1024, 2048, (t == 1 ? qmask : kmask), bOb, Lk[t]);
        }
        gemm(bOb, wa + (9 + t)*MELEM,
             ob + t*1024, ob + t*1024, ob + t*1024, ob + t*1024,
             bM, NX, 1024, 1024, 0);
        ln_res_b<0,1><<<NX, blk, 0, stream>>>(xb, bM, lng + t*1024, lnb + t*1024, xb, nullptr);
    }

    // FFN
    gemm(xb, wa + 12*MELEM, b1, b1 + 1024, b1 + 2048, b1 + 3072, hb, NX, FFD, 1024, 1);
    gemm(hb, wa + 16*MELEM, b2, b2, b2, b2, bM, NX, 1024, 4096, 0);
    ln_res_b<1,0><<<NX, blk, 0, stream>>>(xb, bM, lng + 3*1024, lnb + 3*1024, nullptr, out);
}